// Round 5
// baseline (514.396 us; speedup 1.0000x reference)
//
#include <hip/hip_runtime.h>

#define IN_F   4096
#define OUT_F  4096
#define N_TOK  8192
#define NW     (OUT_F * IN_F)          // 16777216 weight elements
#define SEL_TARGET 8388608u            // 0-based ascending index of kth (= NW - MAX_ITER)
#define CAND_CAP (1u << 20)            // 1M keys (expected ~205K)

// Magnitude window (f32 bit patterns, sign stripped): kth is at the median of
// |w| ~ U[0, 2^-6)  =>  ~2^-7 with sigma ~1.9e-6.  Window is ~±50 sigma.
#define LO_BITS 0x3BFCA000u            // 0.0077133
#define HI_BITS 0x3C018000u            // 0.0079041

typedef unsigned int  u32;
typedef unsigned short u16;

typedef __bf16 bf16x8 __attribute__((ext_vector_type(8)));
typedef float  f32x4  __attribute__((ext_vector_type(4)));

// scal layout: [0]=fb prefix  [1]=fb remaining-rank  [2]=kth bits
//              [3]=win cand count  [4]=count below LO  [5]=fb cand count
//              [6]=win overflow flag  [7]=fallback gate
// ---------- helpers ----------
__device__ inline u16 f2bf_rne(float f) {
    u32 u = __float_as_uint(f);
    u32 r = (u + 0x7fffu + ((u >> 16) & 1u)) >> 16;
    return (u16)r;
}

// ---------- fast path: one scan — count below LO + compact window keys ----------
__global__ __launch_bounds__(256) void scan1_kernel(const uint4* __restrict__ wb,
                                                    u32* __restrict__ cand,
                                                    u32* __restrict__ scal,
                                                    u32* __restrict__ hist16k) {
    __shared__ u32 lbuf[4096];
    __shared__ u32 lcnt, gbase, lblw;
    if (threadIdx.x == 0) { lcnt = 0; lblw = 0; }
    // zero the fallback histogram region (visible to gated hist1 after this kernel)
    if (blockIdx.x < 64) hist16k[blockIdx.x * 256 + threadIdx.x] = 0;
    __syncthreads();

    const int base = blockIdx.x * 4096;   // uint4 units; 1024 blocks * 4096 = NW/4
    u32 cntb = 0;
    #pragma unroll 4
    for (int j = 0; j < 16; j++) {
        uint4 v = wb[base + threadIdx.x + j * 256];
        u32 k[4] = {v.x & 0x7fffffffu, v.y & 0x7fffffffu,
                    v.z & 0x7fffffffu, v.w & 0x7fffffffu};
        #pragma unroll
        for (int e = 0; e < 4; e++) {
            u32 kk = k[e];
            cntb += (kk < LO_BITS) ? 1u : 0u;
            if (kk >= LO_BITS && kk < HI_BITS) {
                u32 idx = atomicAdd(&lcnt, 1u);
                if (idx < 4096) lbuf[idx] = kk;
                else scal[6] = 1u;                 // window overflow -> fallback
            }
        }
    }
    // wave reduce below-count, then one LDS atomic per wave, one global pair per block
    #pragma unroll
    for (int off = 32; off; off >>= 1) cntb += __shfl_down(cntb, off);
    if ((threadIdx.x & 63) == 0) atomicAdd(&lblw, cntb);
    __syncthreads();
    if (threadIdx.x == 0) {
        gbase = atomicAdd(&scal[3], min(lcnt, 4096u));
        atomicAdd(&scal[4], lblw);
    }
    __syncthreads();
    const u32 n = min(lcnt, 4096u), gb = gbase;
    for (u32 i = threadIdx.x; i < n; i += 256)
        if (gb + i < CAND_CAP) cand[gb + i] = lbuf[i];
}

// ---------- fast path: select kth among window candidates (1 block) ----------
#define SCAN1024(part, t)                                            \
    do { _Pragma("unroll")                                           \
        for (int off_ = 1; off_ < 1024; off_ <<= 1) {                \
            u32 v_ = ((t) >= off_) ? part[(t) - off_] : 0u;          \
            __syncthreads();                                         \
            part[t] += v_;                                           \
            __syncthreads();                                         \
        } } while (0)

__global__ __launch_bounds__(1024) void select_win_kernel(const u32* __restrict__ cand,
                                                          u32* __restrict__ scal) {
    __shared__ u32 h[2048];
    __shared__ u32 part[1024];
    __shared__ u32 sh[2];
    const int t = threadIdx.x;
    const u32 n = scal[3], below = scal[4], ovf = scal[6];
    const bool valid = (n > 0) && (n <= CAND_CAP) && (ovf == 0) &&
                       (below <= SEL_TARGET) && (SEL_TARGET < below + n);
    if (!valid) { if (t == 0) scal[7] = 1u; return; }
    u32 tgt = SEL_TARGET - below;

    // L1: 2048 bins over key>>20
    h[2 * t] = 0; h[2 * t + 1] = 0;
    __syncthreads();
    for (u32 i = t; i < n; i += 1024) atomicAdd(&h[cand[i] >> 20], 1u);
    __syncthreads();
    u32 a0 = h[2 * t], a1 = h[2 * t + 1];
    part[t] = a0 + a1;
    __syncthreads();
    SCAN1024(part, t);
    u32 cum = (t == 0) ? 0u : part[t - 1];
    if (tgt >= cum && tgt < cum + a0) { sh[0] = (u32)(2 * t);     sh[1] = tgt - cum; }
    cum += a0;
    if (tgt >= cum && tgt < cum + a1) { sh[0] = (u32)(2 * t + 1); sh[1] = tgt - cum; }
    __syncthreads();
    const u32 b1 = sh[0];
    tgt = sh[1];
    __syncthreads();

    // L2: 1024 bins over (key>>10)&1023, filtered to b1
    h[t] = 0;
    __syncthreads();
    for (u32 i = t; i < n; i += 1024) {
        u32 k = cand[i];
        if ((k >> 20) == b1) atomicAdd(&h[(k >> 10) & 1023u], 1u);
    }
    __syncthreads();
    u32 c = h[t];
    part[t] = c;
    __syncthreads();
    SCAN1024(part, t);
    cum = (t == 0) ? 0u : part[t - 1];
    if (tgt >= cum && tgt < cum + c) { sh[0] = (u32)t; sh[1] = tgt - cum; }
    __syncthreads();
    const u32 pfx20 = (b1 << 10) | sh[0];
    tgt = sh[1];
    __syncthreads();

    // L3: 1024 bins over key&1023, filtered to pfx20
    h[t] = 0;
    __syncthreads();
    for (u32 i = t; i < n; i += 1024) {
        u32 k = cand[i];
        if ((k >> 10) == pfx20) atomicAdd(&h[k & 1023u], 1u);
    }
    __syncthreads();
    c = h[t];
    part[t] = c;
    __syncthreads();
    SCAN1024(part, t);
    cum = (t == 0) ? 0u : part[t - 1];
    if (tgt >= cum && tgt < cum + c) scal[2] = (pfx20 << 10) | (u32)t;   // kth bits
}

// ---------- fallback (exact radix), gated on scal[7] ----------
__global__ __launch_bounds__(1024) void hist1_kernel(const uint4* __restrict__ wb,
                                                     u32* __restrict__ hist,
                                                     const u32* __restrict__ scal) {
    if (scal[7] != 1u) return;
    __shared__ u32 lh[16384];
    for (int i = threadIdx.x; i < 16384; i += 1024) lh[i] = 0;
    __syncthreads();
    const int nvec = NW / 4;
    const int stride = gridDim.x * 1024;
    for (int i = blockIdx.x * 1024 + threadIdx.x; i < nvec; i += stride) {
        uint4 v = wb[i];
        atomicAdd(&lh[(v.x & 0x7fffffffu) >> 17], 1u);
        atomicAdd(&lh[(v.y & 0x7fffffffu) >> 17], 1u);
        atomicAdd(&lh[(v.z & 0x7fffffffu) >> 17], 1u);
        atomicAdd(&lh[(v.w & 0x7fffffffu) >> 17], 1u);
    }
    __syncthreads();
    for (int i = threadIdx.x; i < 16384; i += 1024)
        if (lh[i]) atomicAdd(&hist[i], lh[i]);
}

__global__ __launch_bounds__(1024) void find1_kernel(const u32* __restrict__ hist,
                                                     u32* __restrict__ scal) {
    if (scal[7] != 1u) return;
    __shared__ u32 part[1024];
    const int t = threadIdx.x;
    u32 loc[16];
    u32 s = 0;
    #pragma unroll
    for (int i = 0; i < 16; i++) { loc[i] = hist[t * 16 + i]; s += loc[i]; }
    part[t] = s;
    __syncthreads();
    SCAN1024(part, t);
    u32 cum = (t == 0) ? 0u : part[t - 1];
    #pragma unroll
    for (int i = 0; i < 16; i++) {
        u32 h = loc[i];
        if (SEL_TARGET >= cum && SEL_TARGET < cum + h) {
            scal[0] = (u32)(t * 16 + i);
            scal[1] = SEL_TARGET - cum;
        }
        cum += h;
    }
}

__global__ __launch_bounds__(256) void compact_kernel(const uint4* __restrict__ wb,
                                                      u32* __restrict__ cand,
                                                      u32* __restrict__ scal) {
    if (scal[7] != 1u) return;
    __shared__ u32 lbuf[4096];
    __shared__ u32 lcnt;
    __shared__ u32 gbase;
    if (threadIdx.x == 0) lcnt = 0;
    const u32 pfx = scal[0];
    __syncthreads();
    const int base = blockIdx.x * 1024;
    #pragma unroll
    for (int j = 0; j < 4; j++) {
        uint4 v = wb[base + threadIdx.x + j * 256];
        u32 k[4] = {v.x & 0x7fffffffu, v.y & 0x7fffffffu,
                    v.z & 0x7fffffffu, v.w & 0x7fffffffu};
        #pragma unroll
        for (int e = 0; e < 4; e++) {
            if ((k[e] >> 17) == pfx) {
                u32 idx = atomicAdd(&lcnt, 1u);
                lbuf[idx] = k[e];
            }
        }
    }
    __syncthreads();
    if (threadIdx.x == 0) gbase = atomicAdd(&scal[5], lcnt);
    __syncthreads();
    const u32 n = lcnt, gb = gbase;
    for (u32 i = threadIdx.x; i < n; i += 256)
        if (gb + i < CAND_CAP) cand[gb + i] = lbuf[i];
}

__global__ __launch_bounds__(1024) void select3_kernel(const u32* __restrict__ cand,
                                                       u32* __restrict__ scal) {
    if (scal[7] != 1u) return;
    __shared__ u32 h2[2048];
    __shared__ u32 part[1024];
    __shared__ u32 h3[64];
    __shared__ u32 sh[2];
    const int t = threadIdx.x;
    const u32 n = min(scal[5], CAND_CAP);
    const u32 tgt = scal[1];

    for (int i = t; i < 2048; i += 1024) h2[i] = 0;
    __syncthreads();
    for (u32 i = t; i < n; i += 1024)
        atomicAdd(&h2[(cand[i] >> 6) & 2047u], 1u);
    __syncthreads();
    u32 a0 = h2[t * 2], a1 = h2[t * 2 + 1];
    part[t] = a0 + a1;
    __syncthreads();
    SCAN1024(part, t);
    u32 cum = (t == 0) ? 0u : part[t - 1];
    if (tgt >= cum && tgt < cum + a0) { sh[0] = (u32)(t * 2);     sh[1] = tgt - cum; }
    cum += a0;
    if (tgt >= cum && tgt < cum + a1) { sh[0] = (u32)(t * 2 + 1); sh[1] = tgt - cum; }
    __syncthreads();
    const u32 b2 = sh[0], tgt2 = sh[1];

    if (t < 64) h3[t] = 0;
    __syncthreads();
    for (u32 i = t; i < n; i += 1024) {
        u32 k = cand[i];
        if (((k >> 6) & 2047u) == b2) atomicAdd(&h3[k & 63u], 1u);
    }
    __syncthreads();
    if (t == 0) {
        u32 c = 0;
        #pragma unroll
        for (int b = 0; b < 64; b++) {
            u32 h = h3[b];
            if (tgt2 >= c && tgt2 < c + h)
                scal[2] = (scal[0] << 17) | (b2 << 6) | (u32)b;
            c += h;
        }
    }
}

// ---------- mask + f32->bf16 conversion ----------
__global__ void convert_w_kernel(const uint4* __restrict__ wb,
                                 u16* __restrict__ w16,
                                 const u32* __restrict__ scal) {
    const u32 kth = scal[2];
    const int nvec = NW / 4;
    const int stride = gridDim.x * blockDim.x;
    for (int i = blockIdx.x * blockDim.x + threadIdx.x; i < nvec; i += stride) {
        uint4 v = wb[i];
        ushort4 o;
        o.x = ((v.x & 0x7fffffffu) >= kth) ? f2bf_rne(__uint_as_float(v.x)) : (u16)0;
        o.y = ((v.y & 0x7fffffffu) >= kth) ? f2bf_rne(__uint_as_float(v.y)) : (u16)0;
        o.z = ((v.z & 0x7fffffffu) >= kth) ? f2bf_rne(__uint_as_float(v.z)) : (u16)0;
        o.w = ((v.w & 0x7fffffffu) >= kth) ? f2bf_rne(__uint_as_float(v.w)) : (u16)0;
        *(ushort4*)&w16[(size_t)i * 4] = o;
    }
}

__global__ void convert_x_kernel(const float4* __restrict__ xb,
                                 u16* __restrict__ x16) {
    const int nvec = (N_TOK * IN_F) / 4;
    const int stride = gridDim.x * blockDim.x;
    for (int i = blockIdx.x * blockDim.x + threadIdx.x; i < nvec; i += stride) {
        float4 v = xb[i];
        ushort4 o;
        o.x = f2bf_rne(v.x);
        o.y = f2bf_rne(v.y);
        o.z = f2bf_rne(v.z);
        o.w = f2bf_rne(v.w);
        *(ushort4*)&x16[(size_t)i * 4] = o;
    }
}

// ---------- 256x256 8-phase bf16 MFMA GEMM (m201-style template) ----------
#define BK 64
#define NT (IN_F / BK)   // 64 K-tiles

#define ASLOT(buf, ks) (((buf) * 2 + (ks)) * 8192)
#define BSLOT(buf, ks) (32768 + ((buf) * 2 + (ks)) * 8192)

#define VMCNT(n) asm volatile("s_waitcnt vmcnt(" #n ")" ::: "memory")
#define LGKM0    asm volatile("s_waitcnt lgkmcnt(0)" ::: "memory")
#define SB0      __builtin_amdgcn_sched_barrier(0)
#define BARR()   __builtin_amdgcn_s_barrier()

__global__ __launch_bounds__(512, 2) void gemm8p(
    const u16* __restrict__ A,
    const u16* __restrict__ B,
    const float* __restrict__ bias,
    float* __restrict__ C) {
    __shared__ u16 lds[65536];   // 128 KiB

    const int tid  = threadIdx.x;
    const int lane = tid & 63;
    const int ln15 = lane & 15;
    const int l16  = lane >> 4;
    const int wv   = tid >> 6;
    const int wr   = wv >> 2;
    const int wc   = wv & 3;
    const int wrow = wr * 128;
    const int wcol = wc * 64;

    const int bid = blockIdx.x;
    const int swz = (bid & 7) * 64 + (bid >> 3);
    const int by  = swz >> 4;
    const int bx  = swz & 15;
    const int arow = by * 256;
    const int brow = bx * 256;

    f32x4 acc[8][4];
    #pragma unroll
    for (int m = 0; m < 8; m++)
        #pragma unroll
        for (int n = 0; n < 4; n++)
            acc[m][n] = {0.f, 0.f, 0.f, 0.f};

    #define STAGE(G, rowbase, kt, ks, slot) do {                                        \
        _Pragma("unroll")                                                               \
        for (int i_ = 0; i_ < 2; i_++) {                                                \
            int q_  = tid + i_ * 512;                                                   \
            int r_  = q_ >> 2;                                                          \
            int cs_ = (q_ & 3) ^ ((r_ >> 1) & 3);                                       \
            const u16* src_ = (G) + (size_t)((rowbase) + r_) * IN_F                     \
                              + (kt) * BK + (ks) * 32 + cs_ * 8;                        \
            __builtin_amdgcn_global_load_lds(                                           \
                (const __attribute__((address_space(1))) unsigned int*)src_,            \
                (__attribute__((address_space(3))) unsigned int*)&lds[(slot) + q_ * 8], \
                16, 0, 0);                                                              \
        } } while (0)

    #define READ_A(mh, ks, buf) do {                                                    \
        _Pragma("unroll")                                                               \
        for (int i_ = 0; i_ < 4; i_++) {                                                \
            int row_ = wrow + ((mh) * 4 + i_) * 16 + ln15;                              \
            int cc_  = l16 ^ ((row_ >> 1) & 3);                                         \
            aF[i_] = *(const bf16x8*)&lds[ASLOT(buf, ks) + row_ * 32 + cc_ * 8];        \
        } } while (0)

    #define READ_B(ks, buf) do {                                                       \
        _Pragma("unroll")                                                               \
        for (int i_ = 0; i_ < 4; i_++) {                                                \
            int row_ = wcol + i_ * 16 + ln15;                                           \
            int cc_  = l16 ^ ((row_ >> 1) & 3);                                         \
            bF[i_] = *(const bf16x8*)&lds[BSLOT(buf, ks) + row_ * 32 + cc_ * 8];        \
        } } while (0)

    #define MFMAQ(mh) do {                                                              \
        __builtin_amdgcn_s_setprio(1);                                                  \
        _Pragma("unroll")                                                               \
        for (int i_ = 0; i_ < 4; i_++)                                                  \
            _Pragma("unroll")                                                           \
            for (int n_ = 0; n_ < 4; n_++)                                              \
                acc[(mh) * 4 + i_][n_] = __builtin_amdgcn_mfma_f32_16x16x32_bf16(       \
                    aF[i_], bF[n_], acc[(mh) * 4 + i_][n_], 0, 0, 0);                   \
        __builtin_amdgcn_s_setprio(0);                                                  \
    } while (0)

    STAGE(B, brow, 0, 0, BSLOT(0, 0));
    STAGE(A, arow, 0, 0, ASLOT(0, 0));
    STAGE(B, brow, 0, 1, BSLOT(0, 1));
    STAGE(A, arow, 0, 1, ASLOT(0, 1));
    VMCNT(4);
    STAGE(B, brow, 1, 0, BSLOT(1, 0));
    STAGE(A, arow, 1, 0, ASLOT(1, 0));
    STAGE(B, brow, 1, 1, BSLOT(1, 1));
    VMCNT(6);
    BARR();

    bf16x8 aF[4], bF[4];

    #pragma unroll 1
    for (int it = 0; it < NT / 2; it++) {
        const int t0 = 2 * it;
        const int ka = t0 + 1;
        const int kb = (t0 + 2 < NT) ? t0 + 2 : NT - 1;
        const int kc = (t0 + 3 < NT) ? t0 + 3 : NT - 1;

        READ_A(0, 0, 0); READ_B(0, 0);
        STAGE(A, arow, ka, 1, ASLOT(1, 1));
        BARR(); LGKM0; SB0; MFMAQ(0); SB0; BARR();
        READ_A(1, 0, 0);
        STAGE(B, brow, kb, 0, BSLOT(0, 0));
        BARR(); LGKM0; SB0; MFMAQ(1); SB0; BARR();
        READ_A(0, 1, 0); READ_B(1, 0);
        STAGE(A, arow, kb, 0, ASLOT(0, 0));
        BARR(); LGKM0; SB0; MFMAQ(0); SB0; BARR();
        READ_A(1, 1, 0);
        STAGE(B, brow, kb, 1, BSLOT(0, 1));
        VMCNT(6);
        BARR(); LGKM0; SB0; MFMAQ(1); SB0; BARR();

        READ_A(0, 0, 1); READ_B(0, 1);
        STAGE(A, arow, kb, 1, ASLOT(0, 1));
        BARR(); LGKM0; SB0; MFMAQ(0); SB0; BARR();
        READ_A(1, 0, 1);
        STAGE(B, brow, kc, 0, BSLOT(1, 0));
        BARR(); LGKM0; SB0; MFMAQ(1); SB0; BARR();
        READ_A(0, 1, 1); READ_B(1, 1);
        STAGE(A, arow, kc, 0, ASLOT(1, 0));
        BARR(); LGKM0; SB0; MFMAQ(0); SB0; BARR();
        READ_A(1, 1, 1);
        STAGE(B, brow, kc, 1, BSLOT(1, 1));
        VMCNT(6);
        BARR(); LGKM0; SB0; MFMAQ(1); SB0; BARR();
    }
    VMCNT(0);

    const int cr = l16 * 4;
    #pragma unroll
    for (int n = 0; n < 4; n++) {
        int col = brow + wcol + n * 16 + ln15;
        float bv = bias[col];
        #pragma unroll
        for (int m = 0; m < 8; m++) {
            int r0 = arow + wrow + m * 16 + cr;
            #pragma unroll
            for (int j = 0; j < 4; j++) {
                C[(size_t)(r0 + j) * OUT_F + col] = acc[m][n][j] + bv;
            }
        }
    }
}

// ---------- launch ----------
extern "C" void kernel_launch(void* const* d_in, const int* in_sizes, int n_in,
                              void* d_out, int out_size, void* d_ws, size_t ws_size,
                              hipStream_t stream) {
    const float* x    = (const float*)d_in[0];
    const float* w    = (const float*)d_in[1];
    const float* bias = (const float*)d_in[2];
    float* out = (float*)d_out;

    char* ws = (char*)d_ws;
    u32* scal  = (u32*)(ws + 0);                             // 16 u32
    u16* w16   = (u16*)(ws + 65536);                         // 33.5 MB
    u16* x16   = (u16*)(ws + 65536 + (size_t)NW * 2);        // 67 MB
    // selection scratch overlaps x16 (consumed before convert_x writes it)
    u32* hist16k = (u32*)x16;                                // 64 KB
    u32* cand    = (u32*)((char*)x16 + 131072);              // 4 MB

    hipMemsetAsync(scal, 0, 64, stream);

    scan1_kernel<<<1024, 256, 0, stream>>>((const uint4*)w, cand, scal, hist16k);
    select_win_kernel<<<1, 1024, 0, stream>>>(cand, scal);
    // exact fallback chain (no-ops unless select_win declared the window invalid)
    hist1_kernel<<<256, 1024, 0, stream>>>((const uint4*)w, hist16k, scal);
    find1_kernel<<<1, 1024, 0, stream>>>(hist16k, scal);
    compact_kernel<<<4096, 256, 0, stream>>>((const uint4*)w, cand, scal);
    select3_kernel<<<1, 1024, 0, stream>>>(cand, scal);

    convert_w_kernel<<<2048, 256, 0, stream>>>((const uint4*)w, w16, scal);
    convert_x_kernel<<<2048, 256, 0, stream>>>((const float4*)x, x16);

    gemm8p<<<512, 512, 0, stream>>>(x16, w16, bias, out);
}

// Round 6
// 415.152 us; speedup vs baseline: 1.2391x; 1.2391x over previous
//
#include <hip/hip_runtime.h>

#define IN_F   4096
#define OUT_F  4096
#define N_TOK  8192
#define NW     (OUT_F * IN_F)          // 16777216 weight elements
#define SEL_TARGET 8388608u            // 0-based ascending index of kth (= NW - MAX_ITER)
#define CAND_CAP (1u << 20)            // 1M keys (expected ~205K)

// Magnitude window (f32 bit patterns, sign stripped): kth is the median of
// |w| ~ U[0, 2^-6)  =>  ~2^-7 = 0x3C000000 with sigma ~1.9e-6.  Window ~±50 sigma.
#define LO_BITS 0x3BFCA000u            // 0.0077133
#define HI_BITS 0x3C018000u            // 0.0079041
// window bit-range = 0x4E000 = 319488 -> L1 bins (key-LO)>>9 : 624 bins (<1024)

typedef unsigned int  u32;
typedef unsigned short u16;

typedef __bf16 bf16x8 __attribute__((ext_vector_type(8)));
typedef float  f32x4  __attribute__((ext_vector_type(4)));

// scal layout: [2]=kth bits  [3]=win cand count  [4]=count below LO  [6]=overflow flag
// ---------- helpers ----------
__device__ inline u16 f2bf_rne(float f) {
    u32 u = __float_as_uint(f);
    u32 r = (u + 0x7fffu + ((u >> 16) & 1u)) >> 16;
    return (u16)r;
}

// ---------- pass 1: one BW-bound scan — count below LO + compact window keys ----------
__global__ __launch_bounds__(256) void scan1_kernel(const uint4* __restrict__ wb,
                                                    u32* __restrict__ cand,
                                                    u32* __restrict__ scal) {
    __shared__ u32 lbuf[4096];
    __shared__ u32 lcnt, gbase, lblw;
    if (threadIdx.x == 0) { lcnt = 0; lblw = 0; }
    __syncthreads();

    const int base = blockIdx.x * 4096;   // uint4 units; 1024 blocks * 4096 = NW/4
    u32 cntb = 0;
    #pragma unroll 4
    for (int j = 0; j < 16; j++) {
        uint4 v = wb[base + threadIdx.x + j * 256];
        u32 k[4] = {v.x & 0x7fffffffu, v.y & 0x7fffffffu,
                    v.z & 0x7fffffffu, v.w & 0x7fffffffu};
        #pragma unroll
        for (int e = 0; e < 4; e++) {
            u32 kk = k[e];
            cntb += (kk < LO_BITS) ? 1u : 0u;
            if (kk >= LO_BITS && kk < HI_BITS) {
                u32 idx = atomicAdd(&lcnt, 1u);
                if (idx < 4096) lbuf[idx] = kk;
                else scal[6] = 1u;                 // per-block overflow -> fallback
            }
        }
    }
    #pragma unroll
    for (int off = 32; off; off >>= 1) cntb += __shfl_down(cntb, off);
    if ((threadIdx.x & 63) == 0) atomicAdd(&lblw, cntb);
    __syncthreads();
    if (threadIdx.x == 0) {
        gbase = atomicAdd(&scal[3], min(lcnt, 4096u));
        atomicAdd(&scal[4], lblw);
    }
    __syncthreads();
    const u32 n = min(lcnt, 4096u), gb = gbase;
    for (u32 i = threadIdx.x; i < n; i += 256)
        if (gb + i < CAND_CAP) cand[gb + i] = lbuf[i];
}

// ---------- pass 2: exact kth among window candidates (1 block) ----------
#define SCAN1024(part, t)                                            \
    do { _Pragma("unroll")                                           \
        for (int off_ = 1; off_ < 1024; off_ <<= 1) {                \
            u32 v_ = ((t) >= off_) ? part[(t) - off_] : 0u;          \
            __syncthreads();                                         \
            part[t] += v_;                                           \
            __syncthreads();                                         \
        } } while (0)

__global__ __launch_bounds__(1024) void select_win_kernel(const u32* __restrict__ cand,
                                                          const uint4* __restrict__ wb,
                                                          u32* __restrict__ scal) {
    __shared__ u32 h[2048];
    __shared__ u32 part[1024];
    __shared__ u32 sh[2];
    const int t = threadIdx.x;
    const u32 n = scal[3], below = scal[4], ovf = scal[6];
    const bool valid = (n > 0) && (n <= CAND_CAP) && (ovf == 0) &&
                       (below <= SEL_TARGET) && (SEL_TARGET < below + n);

    if (valid) {
        u32 tgt = SEL_TARGET - below;

        // L1: 624 bins over (key - LO) >> 9  (contention-free: <=512/bin)
        h[t] = 0; h[t + 1024] = 0;
        __syncthreads();
        for (u32 i = t; i < n; i += 1024)
            atomicAdd(&h[(cand[i] - LO_BITS) >> 9], 1u);
        __syncthreads();
        u32 c = h[t];
        part[t] = c;
        __syncthreads();
        SCAN1024(part, t);
        u32 cum = (t == 0) ? 0u : part[t - 1];
        if (tgt >= cum && tgt < cum + c) { sh[0] = (u32)t; sh[1] = tgt - cum; }
        __syncthreads();
        const u32 b1 = sh[0];
        tgt = sh[1];
        __syncthreads();

        // L2: exact — 512 bins over (key - LO) & 511, filtered to b1
        h[t] = 0; h[t + 1024] = 0;
        __syncthreads();
        for (u32 i = t; i < n; i += 1024) {
            u32 d = cand[i] - LO_BITS;
            if ((d >> 9) == b1) atomicAdd(&h[d & 511u], 1u);
        }
        __syncthreads();
        c = (t < 512) ? h[t] : 0u;
        part[t] = c;
        __syncthreads();
        SCAN1024(part, t);
        cum = (t == 0) ? 0u : part[t - 1];
        if (tgt >= cum && tgt < cum + c)
            scal[2] = LO_BITS + (b1 << 9) + (u32)t;   // kth |w| bit pattern
        return;
    }

    // ---- embedded exact fallback (single block, 3-level radix over all keys).
    // Never taken for the expected distribution; correct (slow) otherwise.
    u32 tgt = SEL_TARGET;
    const int nvec = NW / 4;
    // L1: 2048 bins over key>>20
    h[t] = 0; h[t + 1024] = 0;
    __syncthreads();
    for (int i = t; i < nvec; i += 1024) {
        uint4 v = wb[i];
        atomicAdd(&h[(v.x & 0x7fffffffu) >> 20], 1u);
        atomicAdd(&h[(v.y & 0x7fffffffu) >> 20], 1u);
        atomicAdd(&h[(v.z & 0x7fffffffu) >> 20], 1u);
        atomicAdd(&h[(v.w & 0x7fffffffu) >> 20], 1u);
    }
    __syncthreads();
    u32 a0 = h[2 * t], a1 = h[2 * t + 1];
    part[t] = a0 + a1;
    __syncthreads();
    SCAN1024(part, t);
    u32 cum = (t == 0) ? 0u : part[t - 1];
    if (tgt >= cum && tgt < cum + a0) { sh[0] = (u32)(2 * t);     sh[1] = tgt - cum; }
    cum += a0;
    if (tgt >= cum && tgt < cum + a1) { sh[0] = (u32)(2 * t + 1); sh[1] = tgt - cum; }
    __syncthreads();
    const u32 b1f = sh[0];
    tgt = sh[1];
    __syncthreads();

    // L2: 2048 bins over (key>>9)&2047, filtered
    h[t] = 0; h[t + 1024] = 0;
    __syncthreads();
    for (int i = t; i < nvec; i += 1024) {
        uint4 v = wb[i];
        u32 k[4] = {v.x & 0x7fffffffu, v.y & 0x7fffffffu,
                    v.z & 0x7fffffffu, v.w & 0x7fffffffu};
        #pragma unroll
        for (int e = 0; e < 4; e++)
            if ((k[e] >> 20) == b1f) atomicAdd(&h[(k[e] >> 9) & 2047u], 1u);
    }
    __syncthreads();
    a0 = h[2 * t]; a1 = h[2 * t + 1];
    part[t] = a0 + a1;
    __syncthreads();
    SCAN1024(part, t);
    cum = (t == 0) ? 0u : part[t - 1];
    if (tgt >= cum && tgt < cum + a0) { sh[0] = (u32)(2 * t);     sh[1] = tgt - cum; }
    cum += a0;
    if (tgt >= cum && tgt < cum + a1) { sh[0] = (u32)(2 * t + 1); sh[1] = tgt - cum; }
    __syncthreads();
    const u32 pfx22 = (b1f << 11) | sh[0];
    tgt = sh[1];
    __syncthreads();

    // L3: 512 bins over key&511, filtered
    h[t] = 0; h[t + 1024] = 0;
    __syncthreads();
    for (int i = t; i < nvec; i += 1024) {
        uint4 v = wb[i];
        u32 k[4] = {v.x & 0x7fffffffu, v.y & 0x7fffffffu,
                    v.z & 0x7fffffffu, v.w & 0x7fffffffu};
        #pragma unroll
        for (int e = 0; e < 4; e++)
            if ((k[e] >> 9) == pfx22) atomicAdd(&h[k[e] & 511u], 1u);
    }
    __syncthreads();
    u32 c = (t < 512) ? h[t] : 0u;
    part[t] = c;
    __syncthreads();
    SCAN1024(part, t);
    cum = (t == 0) ? 0u : part[t - 1];
    if (tgt >= cum && tgt < cum + c)
        scal[2] = (pfx22 << 9) | (u32)t;
}

// ---------- mask + f32->bf16 conversion ----------
__global__ void convert_w_kernel(const uint4* __restrict__ wb,
                                 u16* __restrict__ w16,
                                 const u32* __restrict__ scal) {
    const u32 kth = scal[2];
    const int nvec = NW / 4;
    const int stride = gridDim.x * blockDim.x;
    for (int i = blockIdx.x * blockDim.x + threadIdx.x; i < nvec; i += stride) {
        uint4 v = wb[i];
        ushort4 o;
        o.x = ((v.x & 0x7fffffffu) >= kth) ? f2bf_rne(__uint_as_float(v.x)) : (u16)0;
        o.y = ((v.y & 0x7fffffffu) >= kth) ? f2bf_rne(__uint_as_float(v.y)) : (u16)0;
        o.z = ((v.z & 0x7fffffffu) >= kth) ? f2bf_rne(__uint_as_float(v.z)) : (u16)0;
        o.w = ((v.w & 0x7fffffffu) >= kth) ? f2bf_rne(__uint_as_float(v.w)) : (u16)0;
        *(ushort4*)&w16[(size_t)i * 4] = o;
    }
}

__global__ void convert_x_kernel(const float4* __restrict__ xb,
                                 u16* __restrict__ x16) {
    const int nvec = (N_TOK * IN_F) / 4;
    const int stride = gridDim.x * blockDim.x;
    for (int i = blockIdx.x * blockDim.x + threadIdx.x; i < nvec; i += stride) {
        float4 v = xb[i];
        ushort4 o;
        o.x = f2bf_rne(v.x);
        o.y = f2bf_rne(v.y);
        o.z = f2bf_rne(v.z);
        o.w = f2bf_rne(v.w);
        *(ushort4*)&x16[(size_t)i * 4] = o;
    }
}

// ---------- 256x256 8-phase bf16 MFMA GEMM (m201-style template) ----------
#define BK 64
#define NT (IN_F / BK)   // 64 K-tiles

#define ASLOT(buf, ks) (((buf) * 2 + (ks)) * 8192)
#define BSLOT(buf, ks) (32768 + ((buf) * 2 + (ks)) * 8192)

#define VMCNT(n) asm volatile("s_waitcnt vmcnt(" #n ")" ::: "memory")
#define LGKM0    asm volatile("s_waitcnt lgkmcnt(0)" ::: "memory")
#define SB0      __builtin_amdgcn_sched_barrier(0)
#define BARR()   __builtin_amdgcn_s_barrier()

__global__ __launch_bounds__(512, 2) void gemm8p(
    const u16* __restrict__ A,
    const u16* __restrict__ B,
    const float* __restrict__ bias,
    float* __restrict__ C) {
    __shared__ u16 lds[65536];   // 128 KiB

    const int tid  = threadIdx.x;
    const int lane = tid & 63;
    const int ln15 = lane & 15;
    const int l16  = lane >> 4;
    const int wv   = tid >> 6;
    const int wr   = wv >> 2;
    const int wc   = wv & 3;
    const int wrow = wr * 128;
    const int wcol = wc * 64;

    const int bid = blockIdx.x;
    const int swz = (bid & 7) * 64 + (bid >> 3);
    const int by  = swz >> 4;
    const int bx  = swz & 15;
    const int arow = by * 256;
    const int brow = bx * 256;

    f32x4 acc[8][4];
    #pragma unroll
    for (int m = 0; m < 8; m++)
        #pragma unroll
        for (int n = 0; n < 4; n++)
            acc[m][n] = {0.f, 0.f, 0.f, 0.f};

    #define STAGE(G, rowbase, kt, ks, slot) do {                                        \
        _Pragma("unroll")                                                               \
        for (int i_ = 0; i_ < 2; i_++) {                                                \
            int q_  = tid + i_ * 512;                                                   \
            int r_  = q_ >> 2;                                                          \
            int cs_ = (q_ & 3) ^ ((r_ >> 1) & 3);                                       \
            const u16* src_ = (G) + (size_t)((rowbase) + r_) * IN_F                     \
                              + (kt) * BK + (ks) * 32 + cs_ * 8;                        \
            __builtin_amdgcn_global_load_lds(                                           \
                (const __attribute__((address_space(1))) unsigned int*)src_,            \
                (__attribute__((address_space(3))) unsigned int*)&lds[(slot) + q_ * 8], \
                16, 0, 0);                                                              \
        } } while (0)

    #define READ_A(mh, ks, buf) do {                                                    \
        _Pragma("unroll")                                                               \
        for (int i_ = 0; i_ < 4; i_++) {                                                \
            int row_ = wrow + ((mh) * 4 + i_) * 16 + ln15;                              \
            int cc_  = l16 ^ ((row_ >> 1) & 3);                                         \
            aF[i_] = *(const bf16x8*)&lds[ASLOT(buf, ks) + row_ * 32 + cc_ * 8];        \
        } } while (0)

    #define READ_B(ks, buf) do {                                                       \
        _Pragma("unroll")                                                               \
        for (int i_ = 0; i_ < 4; i_++) {                                                \
            int row_ = wcol + i_ * 16 + ln15;                                           \
            int cc_  = l16 ^ ((row_ >> 1) & 3);                                         \
            bF[i_] = *(const bf16x8*)&lds[BSLOT(buf, ks) + row_ * 32 + cc_ * 8];        \
        } } while (0)

    #define MFMAQ(mh) do {                                                              \
        __builtin_amdgcn_s_setprio(1);                                                  \
        _Pragma("unroll")                                                               \
        for (int i_ = 0; i_ < 4; i_++)                                                  \
            _Pragma("unroll")                                                           \
            for (int n_ = 0; n_ < 4; n_++)                                              \
                acc[(mh) * 4 + i_][n_] = __builtin_amdgcn_mfma_f32_16x16x32_bf16(       \
                    aF[i_], bF[n_], acc[(mh) * 4 + i_][n_], 0, 0, 0);                   \
        __builtin_amdgcn_s_setprio(0);                                                  \
    } while (0)

    STAGE(B, brow, 0, 0, BSLOT(0, 0));
    STAGE(A, arow, 0, 0, ASLOT(0, 0));
    STAGE(B, brow, 0, 1, BSLOT(0, 1));
    STAGE(A, arow, 0, 1, ASLOT(0, 1));
    VMCNT(4);
    STAGE(B, brow, 1, 0, BSLOT(1, 0));
    STAGE(A, arow, 1, 0, ASLOT(1, 0));
    STAGE(B, brow, 1, 1, BSLOT(1, 1));
    VMCNT(6);
    BARR();

    bf16x8 aF[4], bF[4];

    #pragma unroll 1
    for (int it = 0; it < NT / 2; it++) {
        const int t0 = 2 * it;
        const int ka = t0 + 1;
        const int kb = (t0 + 2 < NT) ? t0 + 2 : NT - 1;
        const int kc = (t0 + 3 < NT) ? t0 + 3 : NT - 1;

        READ_A(0, 0, 0); READ_B(0, 0);
        STAGE(A, arow, ka, 1, ASLOT(1, 1));
        BARR(); LGKM0; SB0; MFMAQ(0); SB0; BARR();
        READ_A(1, 0, 0);
        STAGE(B, brow, kb, 0, BSLOT(0, 0));
        BARR(); LGKM0; SB0; MFMAQ(1); SB0; BARR();
        READ_A(0, 1, 0); READ_B(1, 0);
        STAGE(A, arow, kb, 0, ASLOT(0, 0));
        BARR(); LGKM0; SB0; MFMAQ(0); SB0; BARR();
        READ_A(1, 1, 0);
        STAGE(B, brow, kb, 1, BSLOT(0, 1));
        VMCNT(6);
        BARR(); LGKM0; SB0; MFMAQ(1); SB0; BARR();

        READ_A(0, 0, 1); READ_B(0, 1);
        STAGE(A, arow, kb, 1, ASLOT(0, 1));
        BARR(); LGKM0; SB0; MFMAQ(0); SB0; BARR();
        READ_A(1, 0, 1);
        STAGE(B, brow, kc, 0, BSLOT(1, 0));
        BARR(); LGKM0; SB0; MFMAQ(1); SB0; BARR();
        READ_A(0, 1, 1); READ_B(1, 1);
        STAGE(A, arow, kc, 0, ASLOT(1, 0));
        BARR(); LGKM0; SB0; MFMAQ(0); SB0; BARR();
        READ_A(1, 1, 1);
        STAGE(B, brow, kc, 1, BSLOT(1, 1));
        VMCNT(6);
        BARR(); LGKM0; SB0; MFMAQ(1); SB0; BARR();
    }
    VMCNT(0);

    const int cr = l16 * 4;
    #pragma unroll
    for (int n = 0; n < 4; n++) {
        int col = brow + wcol + n * 16 + ln15;
        float bv = bias[col];
        #pragma unroll
        for (int m = 0; m < 8; m++) {
            int r0 = arow + wrow + m * 16 + cr;
            #pragma unroll
            for (int j = 0; j < 4; j++) {
                C[(size_t)(r0 + j) * OUT_F + col] = acc[m][n][j] + bv;
            }
        }
    }
}

// ---------- launch ----------
extern "C" void kernel_launch(void* const* d_in, const int* in_sizes, int n_in,
                              void* d_out, int out_size, void* d_ws, size_t ws_size,
                              hipStream_t stream) {
    const float* x    = (const float*)d_in[0];
    const float* w    = (const float*)d_in[1];
    const float* bias = (const float*)d_in[2];
    float* out = (float*)d_out;

    char* ws = (char*)d_ws;
    u32* scal  = (u32*)(ws + 0);                             // 16 u32
    u16* w16   = (u16*)(ws + 65536);                         // 33.5 MB
    u16* x16   = (u16*)(ws + 65536 + (size_t)NW * 2);        // 67 MB
    // selection scratch overlaps x16 (consumed before convert_x writes it)
    u32* cand  = (u32*)((char*)x16 + 131072);                // 4 MB

    hipMemsetAsync(scal, 0, 64, stream);

    scan1_kernel<<<1024, 256, 0, stream>>>((const uint4*)w, cand, scal);
    select_win_kernel<<<1, 1024, 0, stream>>>(cand, (const uint4*)w, scal);

    convert_w_kernel<<<2048, 256, 0, stream>>>((const uint4*)w, w16, scal);
    convert_x_kernel<<<2048, 256, 0, stream>>>((const float4*)x, x16);

    gemm8p<<<512, 512, 0, stream>>>(x16, w16, bias, out);
}

// Round 7
// 366.767 us; speedup vs baseline: 1.4025x; 1.1319x over previous
//
#include <hip/hip_runtime.h>

#define IN_F   4096
#define OUT_F  4096
#define N_TOK  8192
#define NW     (OUT_F * IN_F)          // 16777216 weight elements
#define SEL_TARGET 8388608u            // 0-based ascending index of kth (= NW - MAX_ITER)
#define CAND_CAP (1u << 20)            // 1M keys (expected ~205K)

// Magnitude window (f32 bit patterns, sign stripped): kth is the median of
// |w| ~ U[0, 2^-6)  =>  ~2^-7 = 0x3C000000 with sigma ~1.9e-6.  Window ~±50 sigma.
#define LO_BITS 0x3BFCA000u            // 0.0077133
#define HI_BITS 0x3C018000u            // 0.0079041
// window bit-range = 0x4E000 -> L1 bins (key-LO)>>9 : 624 bins (<1024)

typedef unsigned int  u32;
typedef unsigned short u16;

typedef __bf16 bf16x8 __attribute__((ext_vector_type(8)));
typedef float  f32x4  __attribute__((ext_vector_type(4)));

// scal layout: [2]=kth bits  [3]=win cand count  [4]=count below LO  [6]=overflow flag
// ---------- helpers ----------
__device__ inline u16 f2bf_rne(float f) {
    u32 u = __float_as_uint(f);
    u32 r = (u + 0x7fffu + ((u >> 16) & 1u)) >> 16;
    return (u16)r;
}

// ---------- pass 1: one BW-bound scan — count below LO + compact window keys ----------
__global__ __launch_bounds__(256) void scan1_kernel(const uint4* __restrict__ wb,
                                                    u32* __restrict__ cand,
                                                    u32* __restrict__ scal) {
    __shared__ u32 lbuf[4096];
    __shared__ u32 lcnt, gbase, lblw;
    if (threadIdx.x == 0) { lcnt = 0; lblw = 0; }
    __syncthreads();

    const int base = blockIdx.x * 4096;   // uint4 units; 1024 blocks * 4096 = NW/4
    u32 cntb = 0;
    #pragma unroll 4
    for (int j = 0; j < 16; j++) {
        uint4 v = wb[base + threadIdx.x + j * 256];
        u32 k[4] = {v.x & 0x7fffffffu, v.y & 0x7fffffffu,
                    v.z & 0x7fffffffu, v.w & 0x7fffffffu};
        #pragma unroll
        for (int e = 0; e < 4; e++) {
            u32 kk = k[e];
            cntb += (kk < LO_BITS) ? 1u : 0u;
            if (kk >= LO_BITS && kk < HI_BITS) {
                u32 idx = atomicAdd(&lcnt, 1u);
                if (idx < 4096) lbuf[idx] = kk;
                else scal[6] = 1u;                 // per-block overflow -> fallback
            }
        }
    }
    #pragma unroll
    for (int off = 32; off; off >>= 1) cntb += __shfl_down(cntb, off);
    if ((threadIdx.x & 63) == 0) atomicAdd(&lblw, cntb);
    __syncthreads();
    if (threadIdx.x == 0) {
        gbase = atomicAdd(&scal[3], min(lcnt, 4096u));
        atomicAdd(&scal[4], lblw);
    }
    __syncthreads();
    const u32 n = min(lcnt, 4096u), gb = gbase;
    for (u32 i = threadIdx.x; i < n; i += 256)
        if (gb + i < CAND_CAP) cand[gb + i] = lbuf[i];
}

// ---------- pass 2: exact kth among window candidates (1 block) ----------
#define SCAN1024(part, t)                                            \
    do { _Pragma("unroll")                                           \
        for (int off_ = 1; off_ < 1024; off_ <<= 1) {                \
            u32 v_ = ((t) >= off_) ? part[(t) - off_] : 0u;          \
            __syncthreads();                                         \
            part[t] += v_;                                           \
            __syncthreads();                                         \
        } } while (0)

__global__ __launch_bounds__(1024) void select_win_kernel(const u32* __restrict__ cand,
                                                          const uint4* __restrict__ wb,
                                                          u32* __restrict__ scal) {
    __shared__ u32 h[2048];
    __shared__ u32 part[1024];
    __shared__ u32 sh[2];
    const int t = threadIdx.x;
    const u32 n = scal[3], below = scal[4], ovf = scal[6];
    const bool valid = (n > 0) && (n <= CAND_CAP) && (ovf == 0) &&
                       (below <= SEL_TARGET) && (SEL_TARGET < below + n);

    if (valid) {
        u32 tgt = SEL_TARGET - below;
        const uint4* c4 = (const uint4*)cand;
        const u32 n4 = n >> 2;

        // L1: 624 bins over (key - LO) >> 9  (contention-free: <=512/bin)
        h[t] = 0; h[t + 1024] = 0;
        __syncthreads();
        for (u32 i = t; i < n4; i += 1024) {
            uint4 v = c4[i];
            atomicAdd(&h[(v.x - LO_BITS) >> 9], 1u);
            atomicAdd(&h[(v.y - LO_BITS) >> 9], 1u);
            atomicAdd(&h[(v.z - LO_BITS) >> 9], 1u);
            atomicAdd(&h[(v.w - LO_BITS) >> 9], 1u);
        }
        for (u32 i = (n4 << 2) + t; i < n; i += 1024)
            atomicAdd(&h[(cand[i] - LO_BITS) >> 9], 1u);
        __syncthreads();
        u32 c = h[t];
        part[t] = c;
        __syncthreads();
        SCAN1024(part, t);
        u32 cum = (t == 0) ? 0u : part[t - 1];
        if (tgt >= cum && tgt < cum + c) { sh[0] = (u32)t; sh[1] = tgt - cum; }
        __syncthreads();
        const u32 b1 = sh[0];
        tgt = sh[1];
        __syncthreads();

        // L2: exact — 512 bins over (key - LO) & 511, filtered to b1
        h[t] = 0; h[t + 1024] = 0;
        __syncthreads();
        for (u32 i = t; i < n4; i += 1024) {
            uint4 v = c4[i];
            u32 d0 = v.x - LO_BITS, d1 = v.y - LO_BITS,
                d2 = v.z - LO_BITS, d3 = v.w - LO_BITS;
            if ((d0 >> 9) == b1) atomicAdd(&h[d0 & 511u], 1u);
            if ((d1 >> 9) == b1) atomicAdd(&h[d1 & 511u], 1u);
            if ((d2 >> 9) == b1) atomicAdd(&h[d2 & 511u], 1u);
            if ((d3 >> 9) == b1) atomicAdd(&h[d3 & 511u], 1u);
        }
        for (u32 i = (n4 << 2) + t; i < n; i += 1024) {
            u32 d = cand[i] - LO_BITS;
            if ((d >> 9) == b1) atomicAdd(&h[d & 511u], 1u);
        }
        __syncthreads();
        c = (t < 512) ? h[t] : 0u;
        part[t] = c;
        __syncthreads();
        SCAN1024(part, t);
        cum = (t == 0) ? 0u : part[t - 1];
        if (tgt >= cum && tgt < cum + c)
            scal[2] = LO_BITS + (b1 << 9) + (u32)t;   // kth |w| bit pattern
        return;
    }

    // ---- embedded exact fallback (single block, 3-level radix over all keys).
    // Never taken for the expected distribution; correct (slow) otherwise.
    u32 tgt = SEL_TARGET;
    const int nvec = NW / 4;
    h[t] = 0; h[t + 1024] = 0;
    __syncthreads();
    for (int i = t; i < nvec; i += 1024) {
        uint4 v = wb[i];
        atomicAdd(&h[(v.x & 0x7fffffffu) >> 20], 1u);
        atomicAdd(&h[(v.y & 0x7fffffffu) >> 20], 1u);
        atomicAdd(&h[(v.z & 0x7fffffffu) >> 20], 1u);
        atomicAdd(&h[(v.w & 0x7fffffffu) >> 20], 1u);
    }
    __syncthreads();
    u32 a0 = h[2 * t], a1 = h[2 * t + 1];
    part[t] = a0 + a1;
    __syncthreads();
    SCAN1024(part, t);
    u32 cum = (t == 0) ? 0u : part[t - 1];
    if (tgt >= cum && tgt < cum + a0) { sh[0] = (u32)(2 * t);     sh[1] = tgt - cum; }
    cum += a0;
    if (tgt >= cum && tgt < cum + a1) { sh[0] = (u32)(2 * t + 1); sh[1] = tgt - cum; }
    __syncthreads();
    const u32 b1f = sh[0];
    tgt = sh[1];
    __syncthreads();

    h[t] = 0; h[t + 1024] = 0;
    __syncthreads();
    for (int i = t; i < nvec; i += 1024) {
        uint4 v = wb[i];
        u32 k[4] = {v.x & 0x7fffffffu, v.y & 0x7fffffffu,
                    v.z & 0x7fffffffu, v.w & 0x7fffffffu};
        #pragma unroll
        for (int e = 0; e < 4; e++)
            if ((k[e] >> 20) == b1f) atomicAdd(&h[(k[e] >> 9) & 2047u], 1u);
    }
    __syncthreads();
    a0 = h[2 * t]; a1 = h[2 * t + 1];
    part[t] = a0 + a1;
    __syncthreads();
    SCAN1024(part, t);
    cum = (t == 0) ? 0u : part[t - 1];
    if (tgt >= cum && tgt < cum + a0) { sh[0] = (u32)(2 * t);     sh[1] = tgt - cum; }
    cum += a0;
    if (tgt >= cum && tgt < cum + a1) { sh[0] = (u32)(2 * t + 1); sh[1] = tgt - cum; }
    __syncthreads();
    const u32 pfx22 = (b1f << 11) | sh[0];
    tgt = sh[1];
    __syncthreads();

    h[t] = 0; h[t + 1024] = 0;
    __syncthreads();
    for (int i = t; i < nvec; i += 1024) {
        uint4 v = wb[i];
        u32 k[4] = {v.x & 0x7fffffffu, v.y & 0x7fffffffu,
                    v.z & 0x7fffffffu, v.w & 0x7fffffffu};
        #pragma unroll
        for (int e = 0; e < 4; e++)
            if ((k[e] >> 9) == pfx22) atomicAdd(&h[k[e] & 511u], 1u);
    }
    __syncthreads();
    u32 c = (t < 512) ? h[t] : 0u;
    part[t] = c;
    __syncthreads();
    SCAN1024(part, t);
    cum = (t == 0) ? 0u : part[t - 1];
    if (tgt >= cum && tgt < cum + c)
        scal[2] = (pfx22 << 9) | (u32)t;
}

// ---------- fused mask+convert: blocks 0-1023 do w, 1024-3071 do x ----------
__global__ __launch_bounds__(256) void convert_fused_kernel(
    const uint4* __restrict__ wb, const float4* __restrict__ xb,
    u16* __restrict__ w16, u16* __restrict__ x16,
    const u32* __restrict__ scal) {
    if (blockIdx.x < 1024) {
        const u32 kth = scal[2];
        const int stride = 1024 * 256;
        for (int i = blockIdx.x * 256 + threadIdx.x; i < NW / 4; i += stride) {
            uint4 v = wb[i];
            ushort4 o;
            o.x = ((v.x & 0x7fffffffu) >= kth) ? f2bf_rne(__uint_as_float(v.x)) : (u16)0;
            o.y = ((v.y & 0x7fffffffu) >= kth) ? f2bf_rne(__uint_as_float(v.y)) : (u16)0;
            o.z = ((v.z & 0x7fffffffu) >= kth) ? f2bf_rne(__uint_as_float(v.z)) : (u16)0;
            o.w = ((v.w & 0x7fffffffu) >= kth) ? f2bf_rne(__uint_as_float(v.w)) : (u16)0;
            *(ushort4*)&w16[(size_t)i * 4] = o;
        }
    } else {
        const int stride = 2048 * 256;
        for (int i = (blockIdx.x - 1024) * 256 + threadIdx.x;
             i < (N_TOK * IN_F) / 4; i += stride) {
            float4 v = xb[i];
            ushort4 o;
            o.x = f2bf_rne(v.x);
            o.y = f2bf_rne(v.y);
            o.z = f2bf_rne(v.z);
            o.w = f2bf_rne(v.w);
            *(ushort4*)&x16[(size_t)i * 4] = o;
        }
    }
}

// ---------- 256x256 8-phase bf16 MFMA GEMM (m201 template, no sched_barrier) ----------
#define BK 64
#define NT (IN_F / BK)   // 64 K-tiles

#define ASLOT(buf, ks) (((buf) * 2 + (ks)) * 8192)
#define BSLOT(buf, ks) (32768 + ((buf) * 2 + (ks)) * 8192)

#define VMCNT(n) asm volatile("s_waitcnt vmcnt(" #n ")" ::: "memory")
#define LGKM0    asm volatile("s_waitcnt lgkmcnt(0)" ::: "memory")
#define BARR()   __builtin_amdgcn_s_barrier()

__global__ __launch_bounds__(512, 2) void gemm8p(
    const u16* __restrict__ A,
    const u16* __restrict__ B,
    const float* __restrict__ bias,
    float* __restrict__ C) {
    __shared__ u16 lds[65536];   // 128 KiB

    const int tid  = threadIdx.x;
    const int lane = tid & 63;
    const int ln15 = lane & 15;
    const int l16  = lane >> 4;
    const int wv   = tid >> 6;
    const int wr   = wv >> 2;
    const int wc   = wv & 3;
    const int wrow = wr * 128;
    const int wcol = wc * 64;

    const int bid = blockIdx.x;
    const int swz = (bid & 7) * 64 + (bid >> 3);
    const int by  = swz >> 4;
    const int bx  = swz & 15;
    const int arow = by * 256;
    const int brow = bx * 256;

    f32x4 acc[8][4];
    #pragma unroll
    for (int m = 0; m < 8; m++)
        #pragma unroll
        for (int n = 0; n < 4; n++)
            acc[m][n] = {0.f, 0.f, 0.f, 0.f};

    #define STAGE(G, rowbase, kt, ks, slot) do {                                        \
        _Pragma("unroll")                                                               \
        for (int i_ = 0; i_ < 2; i_++) {                                                \
            int q_  = tid + i_ * 512;                                                   \
            int r_  = q_ >> 2;                                                          \
            int cs_ = (q_ & 3) ^ ((r_ >> 1) & 3);                                       \
            const u16* src_ = (G) + (size_t)((rowbase) + r_) * IN_F                     \
                              + (kt) * BK + (ks) * 32 + cs_ * 8;                        \
            __builtin_amdgcn_global_load_lds(                                           \
                (const __attribute__((address_space(1))) unsigned int*)src_,            \
                (__attribute__((address_space(3))) unsigned int*)&lds[(slot) + q_ * 8], \
                16, 0, 0);                                                              \
        } } while (0)

    #define READ_A(mh, ks, buf) do {                                                    \
        _Pragma("unroll")                                                               \
        for (int i_ = 0; i_ < 4; i_++) {                                                \
            int row_ = wrow + ((mh) * 4 + i_) * 16 + ln15;                              \
            int cc_  = l16 ^ ((row_ >> 1) & 3);                                         \
            aF[i_] = *(const bf16x8*)&lds[ASLOT(buf, ks) + row_ * 32 + cc_ * 8];        \
        } } while (0)

    #define READ_B(ks, buf) do {                                                       \
        _Pragma("unroll")                                                               \
        for (int i_ = 0; i_ < 4; i_++) {                                                \
            int row_ = wcol + i_ * 16 + ln15;                                           \
            int cc_  = l16 ^ ((row_ >> 1) & 3);                                         \
            bF[i_] = *(const bf16x8*)&lds[BSLOT(buf, ks) + row_ * 32 + cc_ * 8];        \
        } } while (0)

    #define MFMAQ(mh) do {                                                              \
        __builtin_amdgcn_s_setprio(1);                                                  \
        _Pragma("unroll")                                                               \
        for (int i_ = 0; i_ < 4; i_++)                                                  \
            _Pragma("unroll")                                                           \
            for (int n_ = 0; n_ < 4; n_++)                                              \
                acc[(mh) * 4 + i_][n_] = __builtin_amdgcn_mfma_f32_16x16x32_bf16(       \
                    aF[i_], bF[n_], acc[(mh) * 4 + i_][n_], 0, 0, 0);                   \
        __builtin_amdgcn_s_setprio(0);                                                  \
    } while (0)

    STAGE(B, brow, 0, 0, BSLOT(0, 0));
    STAGE(A, arow, 0, 0, ASLOT(0, 0));
    STAGE(B, brow, 0, 1, BSLOT(0, 1));
    STAGE(A, arow, 0, 1, ASLOT(0, 1));
    VMCNT(4);
    STAGE(B, brow, 1, 0, BSLOT(1, 0));
    STAGE(A, arow, 1, 0, ASLOT(1, 0));
    STAGE(B, brow, 1, 1, BSLOT(1, 1));
    VMCNT(6);
    BARR();

    bf16x8 aF[4], bF[4];

    #pragma unroll 1
    for (int it = 0; it < NT / 2; it++) {
        const int t0 = 2 * it;
        const int ka = t0 + 1;
        const int kb = (t0 + 2 < NT) ? t0 + 2 : NT - 1;
        const int kc = (t0 + 3 < NT) ? t0 + 3 : NT - 1;

        READ_A(0, 0, 0); READ_B(0, 0);
        STAGE(A, arow, ka, 1, ASLOT(1, 1));
        BARR(); LGKM0; MFMAQ(0); BARR();
        READ_A(1, 0, 0);
        STAGE(B, brow, kb, 0, BSLOT(0, 0));
        BARR(); LGKM0; MFMAQ(1); BARR();
        READ_A(0, 1, 0); READ_B(1, 0);
        STAGE(A, arow, kb, 0, ASLOT(0, 0));
        BARR(); LGKM0; MFMAQ(0); BARR();
        READ_A(1, 1, 0);
        STAGE(B, brow, kb, 1, BSLOT(0, 1));
        VMCNT(6);
        BARR(); LGKM0; MFMAQ(1); BARR();

        READ_A(0, 0, 1); READ_B(0, 1);
        STAGE(A, arow, kb, 1, ASLOT(0, 1));
        BARR(); LGKM0; MFMAQ(0); BARR();
        READ_A(1, 0, 1);
        STAGE(B, brow, kc, 0, BSLOT(1, 0));
        BARR(); LGKM0; MFMAQ(1); BARR();
        READ_A(0, 1, 1); READ_B(1, 1);
        STAGE(A, arow, kc, 0, ASLOT(1, 0));
        BARR(); LGKM0; MFMAQ(0); BARR();
        READ_A(1, 1, 1);
        STAGE(B, brow, kc, 1, BSLOT(1, 1));
        VMCNT(6);
        BARR(); LGKM0; MFMAQ(1); BARR();
    }
    VMCNT(0);

    const int cr = l16 * 4;
    #pragma unroll
    for (int n = 0; n < 4; n++) {
        int col = brow + wcol + n * 16 + ln15;
        float bv = bias[col];
        #pragma unroll
        for (int m = 0; m < 8; m++) {
            int r0 = arow + wrow + m * 16 + cr;
            #pragma unroll
            for (int j = 0; j < 4; j++) {
                C[(size_t)(r0 + j) * OUT_F + col] = acc[m][n][j] + bv;
            }
        }
    }
}

// ---------- launch ----------
extern "C" void kernel_launch(void* const* d_in, const int* in_sizes, int n_in,
                              void* d_out, int out_size, void* d_ws, size_t ws_size,
                              hipStream_t stream) {
    const float* x    = (const float*)d_in[0];
    const float* w    = (const float*)d_in[1];
    const float* bias = (const float*)d_in[2];
    float* out = (float*)d_out;

    char* ws = (char*)d_ws;
    u32* scal  = (u32*)(ws + 0);                             // 16 u32
    u16* w16   = (u16*)(ws + 65536);                         // 33.5 MB
    u16* x16   = (u16*)(ws + 65536 + (size_t)NW * 2);        // 67 MB
    // selection scratch overlaps x16 (dead before convert writes x16)
    u32* cand  = (u32*)((char*)x16 + 131072);                // 4 MB

    hipMemsetAsync(scal, 0, 64, stream);

    scan1_kernel<<<1024, 256, 0, stream>>>((const uint4*)w, cand, scal);
    select_win_kernel<<<1, 1024, 0, stream>>>(cand, (const uint4*)w, scal);

    convert_fused_kernel<<<3072, 256, 0, stream>>>((const uint4*)w, (const float4*)x,
                                                   w16, x16, scal);

    gemm8p<<<512, 512, 0, stream>>>(x16, w16, bias, out);
}

// Round 9
// 347.614 us; speedup vs baseline: 1.4798x; 1.0551x over previous
//
#include <hip/hip_runtime.h>

#define IN_F   4096
#define OUT_F  4096
#define N_TOK  8192
#define NW     (OUT_F * IN_F)          // 16777216 weight elements
#define SEL_TARGET 8388608u            // 0-based ascending index of kth (= NW - MAX_ITER)
#define CAND_CAP (1u << 20)            // 1M keys (expected ~205K)

// Magnitude window (f32 bit patterns, sign stripped): kth is the median of
// |w| ~ U[0, 2^-6)  =>  ~2^-7 = 0x3C000000 with sigma ~1.9e-6.  Window ~±50 sigma.
#define LO_BITS 0x3BFCA000u            // 0.0077133
#define HI_BITS 0x3C018000u            // 0.0079041

typedef unsigned int  u32;
typedef unsigned short u16;

typedef __bf16 bf16x8 __attribute__((ext_vector_type(8)));
typedef float  f32x4  __attribute__((ext_vector_type(4)));
typedef u32    u32x4  __attribute__((ext_vector_type(4)));   // nt-load capable

// scal layout: [2]=kth bits  [3]=win cand count  [4]=count below LO  [6]=overflow flag
// ---------- helpers ----------
__device__ inline u16 f2bf_rne(float f) {
    u32 u = __float_as_uint(f);
    u32 r = (u + 0x7fffu + ((u >> 16) & 1u)) >> 16;
    return (u16)r;
}

// ---------- fused front-end: blocks 0-1023 scan w (count-below + window compact),
// ---------- blocks 1024-3071 convert x -> bf16 (independent of kth) ----------
__global__ __launch_bounds__(256) void front_fused_kernel(
    const uint4* __restrict__ wb, const f32x4* __restrict__ xb,
    u32* __restrict__ cand, u16* __restrict__ x16,
    u32* __restrict__ scal) {
    if (blockIdx.x < 1024) {
        __shared__ u32 lbuf[4096];
        __shared__ u32 lcnt, gbase, lblw;
        if (threadIdx.x == 0) { lcnt = 0; lblw = 0; }
        __syncthreads();

        const int base = blockIdx.x * 4096;   // uint4 units; 1024 blocks * 4096 = NW/4
        u32 cntb = 0;
        #pragma unroll 4
        for (int j = 0; j < 16; j++) {
            uint4 v = wb[base + threadIdx.x + j * 256];
            u32 k[4] = {v.x & 0x7fffffffu, v.y & 0x7fffffffu,
                        v.z & 0x7fffffffu, v.w & 0x7fffffffu};
            #pragma unroll
            for (int e = 0; e < 4; e++) {
                u32 kk = k[e];
                cntb += (kk < LO_BITS) ? 1u : 0u;
                if (kk >= LO_BITS && kk < HI_BITS) {
                    u32 idx = atomicAdd(&lcnt, 1u);
                    if (idx < 4096) lbuf[idx] = kk;
                    else scal[6] = 1u;                 // per-block overflow -> fallback
                }
            }
        }
        #pragma unroll
        for (int off = 32; off; off >>= 1) cntb += __shfl_down(cntb, off);
        if ((threadIdx.x & 63) == 0) atomicAdd(&lblw, cntb);
        __syncthreads();
        if (threadIdx.x == 0) {
            gbase = atomicAdd(&scal[3], min(lcnt, 4096u));
            atomicAdd(&scal[4], lblw);
        }
        __syncthreads();
        const u32 n = min(lcnt, 4096u), gb = gbase;
        for (u32 i = threadIdx.x; i < n; i += 256)
            if (gb + i < CAND_CAP) cand[gb + i] = lbuf[i];
    } else {
        const int stride = 2048 * 256;
        for (int i = (blockIdx.x - 1024) * 256 + threadIdx.x;
             i < (N_TOK * IN_F) / 4; i += stride) {
            f32x4 v = __builtin_nontemporal_load(&xb[i]);   // read-once stream
            ushort4 o;
            o.x = f2bf_rne(v.x);
            o.y = f2bf_rne(v.y);
            o.z = f2bf_rne(v.z);
            o.w = f2bf_rne(v.w);
            *(ushort4*)&x16[(size_t)i * 4] = o;
        }
    }
}

// ---------- exact kth among window candidates (1 block) ----------
#define SCAN1024(part, t)                                            \
    do { _Pragma("unroll")                                           \
        for (int off_ = 1; off_ < 1024; off_ <<= 1) {                \
            u32 v_ = ((t) >= off_) ? part[(t) - off_] : 0u;          \
            __syncthreads();                                         \
            part[t] += v_;                                           \
            __syncthreads();                                         \
        } } while (0)

__global__ __launch_bounds__(1024) void select_win_kernel(const u32* __restrict__ cand,
                                                          const uint4* __restrict__ wb,
                                                          u32* __restrict__ scal) {
    __shared__ u32 h[2048];
    __shared__ u32 part[1024];
    __shared__ u32 sh[2];
    const int t = threadIdx.x;
    const u32 n = scal[3], below = scal[4], ovf = scal[6];
    const bool valid = (n > 0) && (n <= CAND_CAP) && (ovf == 0) &&
                       (below <= SEL_TARGET) && (SEL_TARGET < below + n);

    if (valid) {
        u32 tgt = SEL_TARGET - below;
        const uint4* c4 = (const uint4*)cand;
        const u32 n4 = n >> 2;

        // L1: 624 bins over (key - LO) >> 9  (contention-free: <=512/bin)
        h[t] = 0; h[t + 1024] = 0;
        __syncthreads();
        for (u32 i = t; i < n4; i += 1024) {
            uint4 v = c4[i];
            atomicAdd(&h[(v.x - LO_BITS) >> 9], 1u);
            atomicAdd(&h[(v.y - LO_BITS) >> 9], 1u);
            atomicAdd(&h[(v.z - LO_BITS) >> 9], 1u);
            atomicAdd(&h[(v.w - LO_BITS) >> 9], 1u);
        }
        for (u32 i = (n4 << 2) + t; i < n; i += 1024)
            atomicAdd(&h[(cand[i] - LO_BITS) >> 9], 1u);
        __syncthreads();
        u32 c = h[t];
        part[t] = c;
        __syncthreads();
        SCAN1024(part, t);
        u32 cum = (t == 0) ? 0u : part[t - 1];
        if (tgt >= cum && tgt < cum + c) { sh[0] = (u32)t; sh[1] = tgt - cum; }
        __syncthreads();
        const u32 b1 = sh[0];
        tgt = sh[1];
        __syncthreads();

        // L2: exact — 512 bins over (key - LO) & 511, filtered to b1
        h[t] = 0; h[t + 1024] = 0;
        __syncthreads();
        for (u32 i = t; i < n4; i += 1024) {
            uint4 v = c4[i];
            u32 d0 = v.x - LO_BITS, d1 = v.y - LO_BITS,
                d2 = v.z - LO_BITS, d3 = v.w - LO_BITS;
            if ((d0 >> 9) == b1) atomicAdd(&h[d0 & 511u], 1u);
            if ((d1 >> 9) == b1) atomicAdd(&h[d1 & 511u], 1u);
            if ((d2 >> 9) == b1) atomicAdd(&h[d2 & 511u], 1u);
            if ((d3 >> 9) == b1) atomicAdd(&h[d3 & 511u], 1u);
        }
        for (u32 i = (n4 << 2) + t; i < n; i += 1024) {
            u32 d = cand[i] - LO_BITS;
            if ((d >> 9) == b1) atomicAdd(&h[d & 511u], 1u);
        }
        __syncthreads();
        c = (t < 512) ? h[t] : 0u;
        part[t] = c;
        __syncthreads();
        SCAN1024(part, t);
        cum = (t == 0) ? 0u : part[t - 1];
        if (tgt >= cum && tgt < cum + c)
            scal[2] = LO_BITS + (b1 << 9) + (u32)t;   // kth |w| bit pattern
        return;
    }

    // ---- embedded exact fallback (single block, 3-level radix over all keys).
    // Never taken for the expected distribution; correct (slow) otherwise.
    u32 tgt = SEL_TARGET;
    const int nvec = NW / 4;
    h[t] = 0; h[t + 1024] = 0;
    __syncthreads();
    for (int i = t; i < nvec; i += 1024) {
        uint4 v = wb[i];
        atomicAdd(&h[(v.x & 0x7fffffffu) >> 20], 1u);
        atomicAdd(&h[(v.y & 0x7fffffffu) >> 20], 1u);
        atomicAdd(&h[(v.z & 0x7fffffffu) >> 20], 1u);
        atomicAdd(&h[(v.w & 0x7fffffffu) >> 20], 1u);
    }
    __syncthreads();
    u32 a0 = h[2 * t], a1 = h[2 * t + 1];
    part[t] = a0 + a1;
    __syncthreads();
    SCAN1024(part, t);
    u32 cum = (t == 0) ? 0u : part[t - 1];
    if (tgt >= cum && tgt < cum + a0) { sh[0] = (u32)(2 * t);     sh[1] = tgt - cum; }
    cum += a0;
    if (tgt >= cum && tgt < cum + a1) { sh[0] = (u32)(2 * t + 1); sh[1] = tgt - cum; }
    __syncthreads();
    const u32 b1f = sh[0];
    tgt = sh[1];
    __syncthreads();

    h[t] = 0; h[t + 1024] = 0;
    __syncthreads();
    for (int i = t; i < nvec; i += 1024) {
        uint4 v = wb[i];
        u32 k[4] = {v.x & 0x7fffffffu, v.y & 0x7fffffffu,
                    v.z & 0x7fffffffu, v.w & 0x7fffffffu};
        #pragma unroll
        for (int e = 0; e < 4; e++)
            if ((k[e] >> 20) == b1f) atomicAdd(&h[(k[e] >> 9) & 2047u], 1u);
    }
    __syncthreads();
    a0 = h[2 * t]; a1 = h[2 * t + 1];
    part[t] = a0 + a1;
    __syncthreads();
    SCAN1024(part, t);
    cum = (t == 0) ? 0u : part[t - 1];
    if (tgt >= cum && tgt < cum + a0) { sh[0] = (u32)(2 * t);     sh[1] = tgt - cum; }
    cum += a0;
    if (tgt >= cum && tgt < cum + a1) { sh[0] = (u32)(2 * t + 1); sh[1] = tgt - cum; }
    __syncthreads();
    const u32 pfx22 = (b1f << 11) | sh[0];
    tgt = sh[1];
    __syncthreads();

    h[t] = 0; h[t + 1024] = 0;
    __syncthreads();
    for (int i = t; i < nvec; i += 1024) {
        uint4 v = wb[i];
        u32 k[4] = {v.x & 0x7fffffffu, v.y & 0x7fffffffu,
                    v.z & 0x7fffffffu, v.w & 0x7fffffffu};
        #pragma unroll
        for (int e = 0; e < 4; e++)
            if ((k[e] >> 9) == pfx22) atomicAdd(&h[k[e] & 511u], 1u);
    }
    __syncthreads();
    u32 c = (t < 512) ? h[t] : 0u;
    part[t] = c;
    __syncthreads();
    SCAN1024(part, t);
    cum = (t == 0) ? 0u : part[t - 1];
    if (tgt >= cum && tgt < cum + c)
        scal[2] = (pfx22 << 9) | (u32)t;
}

// ---------- mask + f32->bf16 weight conversion ----------
__global__ __launch_bounds__(256) void convert_w_kernel(const u32x4* __restrict__ wb,
                                                        u16* __restrict__ w16,
                                                        const u32* __restrict__ scal) {
    const u32 kth = scal[2];
    const int nvec = NW / 4;
    const int stride = gridDim.x * blockDim.x;
    for (int i = blockIdx.x * blockDim.x + threadIdx.x; i < nvec; i += stride) {
        u32x4 v = __builtin_nontemporal_load(&wb[i]);   // w dead after this pass
        ushort4 o;
        o.x = ((v.x & 0x7fffffffu) >= kth) ? f2bf_rne(__uint_as_float(v.x)) : (u16)0;
        o.y = ((v.y & 0x7fffffffu) >= kth) ? f2bf_rne(__uint_as_float(v.y)) : (u16)0;
        o.z = ((v.z & 0x7fffffffu) >= kth) ? f2bf_rne(__uint_as_float(v.z)) : (u16)0;
        o.w = ((v.w & 0x7fffffffu) >= kth) ? f2bf_rne(__uint_as_float(v.w)) : (u16)0;
        *(ushort4*)&w16[(size_t)i * 4] = o;
    }
}

// ---------- 256x256 8-phase bf16 MFMA GEMM (m201 template) ----------
#define BK 64
#define NT (IN_F / BK)   // 64 K-tiles

#define ASLOT(buf, ks) (((buf) * 2 + (ks)) * 8192)
#define BSLOT(buf, ks) (32768 + ((buf) * 2 + (ks)) * 8192)

#define VMCNT(n) asm volatile("s_waitcnt vmcnt(" #n ")" ::: "memory")
#define LGKM0    asm volatile("s_waitcnt lgkmcnt(0)" ::: "memory")
#define BARR()   __builtin_amdgcn_s_barrier()

__global__ __launch_bounds__(512, 2) void gemm8p(
    const u16* __restrict__ A,
    const u16* __restrict__ B,
    const float* __restrict__ bias,
    float* __restrict__ C) {
    __shared__ u16 lds[65536];   // 128 KiB

    const int tid  = threadIdx.x;
    const int lane = tid & 63;
    const int ln15 = lane & 15;
    const int l16  = lane >> 4;
    const int wv   = tid >> 6;
    const int wr   = wv >> 2;
    const int wc   = wv & 3;
    const int wrow = wr * 128;
    const int wcol = wc * 64;

    const int bid = blockIdx.x;
    const int swz = (bid & 7) * 64 + (bid >> 3);
    const int by  = swz >> 4;
    const int bx  = swz & 15;
    const int arow = by * 256;
    const int brow = bx * 256;

    f32x4 acc[8][4];
    #pragma unroll
    for (int m = 0; m < 8; m++)
        #pragma unroll
        for (int n = 0; n < 4; n++)
            acc[m][n] = {0.f, 0.f, 0.f, 0.f};

    #define STAGE(G, rowbase, kt, ks, slot) do {                                        \
        _Pragma("unroll")                                                               \
        for (int i_ = 0; i_ < 2; i_++) {                                                \
            int q_  = tid + i_ * 512;                                                   \
            int r_  = q_ >> 2;                                                          \
            int cs_ = (q_ & 3) ^ ((r_ >> 1) & 3);                                       \
            const u16* src_ = (G) + (size_t)((rowbase) + r_) * IN_F                     \
                              + (kt) * BK + (ks) * 32 + cs_ * 8;                        \
            __builtin_amdgcn_global_load_lds(                                           \
                (const __attribute__((address_space(1))) unsigned int*)src_,            \
                (__attribute__((address_space(3))) unsigned int*)&lds[(slot) + q_ * 8], \
                16, 0, 0);                                                              \
        } } while (0)

    #define READ_A(mh, ks, buf) do {                                                    \
        _Pragma("unroll")                                                               \
        for (int i_ = 0; i_ < 4; i_++) {                                                \
            int row_ = wrow + ((mh) * 4 + i_) * 16 + ln15;                              \
            int cc_  = l16 ^ ((row_ >> 1) & 3);                                         \
            aF[i_] = *(const bf16x8*)&lds[ASLOT(buf, ks) + row_ * 32 + cc_ * 8];        \
        } } while (0)

    #define READ_B(ks, buf) do {                                                       \
        _Pragma("unroll")                                                               \
        for (int i_ = 0; i_ < 4; i_++) {                                                \
            int row_ = wcol + i_ * 16 + ln15;                                           \
            int cc_  = l16 ^ ((row_ >> 1) & 3);                                         \
            bF[i_] = *(const bf16x8*)&lds[BSLOT(buf, ks) + row_ * 32 + cc_ * 8];        \
        } } while (0)

    #define MFMAQ(mh) do {                                                              \
        __builtin_amdgcn_s_setprio(1);                                                  \
        _Pragma("unroll")                                                               \
        for (int i_ = 0; i_ < 4; i_++)                                                  \
            _Pragma("unroll")                                                           \
            for (int n_ = 0; n_ < 4; n_++)                                              \
                acc[(mh) * 4 + i_][n_] = __builtin_amdgcn_mfma_f32_16x16x32_bf16(       \
                    aF[i_], bF[n_], acc[(mh) * 4 + i_][n_], 0, 0, 0);                   \
        __builtin_amdgcn_s_setprio(0);                                                  \
    } while (0)

    STAGE(B, brow, 0, 0, BSLOT(0, 0));
    STAGE(A, arow, 0, 0, ASLOT(0, 0));
    STAGE(B, brow, 0, 1, BSLOT(0, 1));
    STAGE(A, arow, 0, 1, ASLOT(0, 1));
    VMCNT(4);
    STAGE(B, brow, 1, 0, BSLOT(1, 0));
    STAGE(A, arow, 1, 0, ASLOT(1, 0));
    STAGE(B, brow, 1, 1, BSLOT(1, 1));
    VMCNT(6);
    BARR();

    bf16x8 aF[4], bF[4];

    #pragma unroll 1
    for (int it = 0; it < NT / 2; it++) {
        const int t0 = 2 * it;
        const int ka = t0 + 1;
        const int kb = (t0 + 2 < NT) ? t0 + 2 : NT - 1;
        const int kc = (t0 + 3 < NT) ? t0 + 3 : NT - 1;

        READ_A(0, 0, 0); READ_B(0, 0);
        STAGE(A, arow, ka, 1, ASLOT(1, 1));
        BARR(); LGKM0; MFMAQ(0); BARR();
        READ_A(1, 0, 0);
        STAGE(B, brow, kb, 0, BSLOT(0, 0));
        BARR(); LGKM0; MFMAQ(1); BARR();
        READ_A(0, 1, 0); READ_B(1, 0);
        STAGE(A, arow, kb, 0, ASLOT(0, 0));
        BARR(); LGKM0; MFMAQ(0); BARR();
        READ_A(1, 1, 0);
        STAGE(B, brow, kb, 1, BSLOT(0, 1));
        VMCNT(6);
        BARR(); LGKM0; MFMAQ(1); BARR();

        READ_A(0, 0, 1); READ_B(0, 1);
        STAGE(A, arow, kb, 1, ASLOT(0, 1));
        BARR(); LGKM0; MFMAQ(0); BARR();
        READ_A(1, 0, 1);
        STAGE(B, brow, kc, 0, BSLOT(1, 0));
        BARR(); LGKM0; MFMAQ(1); BARR();
        READ_A(0, 1, 1); READ_B(1, 1);
        STAGE(A, arow, kc, 0, ASLOT(1, 0));
        BARR(); LGKM0; MFMAQ(0); BARR();
        READ_A(1, 1, 1);
        STAGE(B, brow, kc, 1, BSLOT(1, 1));
        VMCNT(6);
        BARR(); LGKM0; MFMAQ(1); BARR();
    }
    VMCNT(0);

    // epilogue: nt stores — C is never re-read; keep L2/L3 for A/B panels
    const int cr = l16 * 4;
    #pragma unroll
    for (int n = 0; n < 4; n++) {
        int col = brow + wcol + n * 16 + ln15;
        float bv = bias[col];
        #pragma unroll
        for (int m = 0; m < 8; m++) {
            int r0 = arow + wrow + m * 16 + cr;
            #pragma unroll
            for (int j = 0; j < 4; j++) {
                float vv = acc[m][n][j] + bv;
                __builtin_nontemporal_store(vv, &C[(size_t)(r0 + j) * OUT_F + col]);
            }
        }
    }
}

// ---------- launch ----------
extern "C" void kernel_launch(void* const* d_in, const int* in_sizes, int n_in,
                              void* d_out, int out_size, void* d_ws, size_t ws_size,
                              hipStream_t stream) {
    const float* x    = (const float*)d_in[0];
    const float* w    = (const float*)d_in[1];
    const float* bias = (const float*)d_in[2];
    float* out = (float*)d_out;

    char* ws = (char*)d_ws;
    u32* scal  = (u32*)(ws + 0);                             // 16 u32
    u16* w16   = (u16*)(ws + 65536);                         // 33.5 MB
    u16* x16   = (u16*)(ws + 65536 + (size_t)NW * 2);        // 67 MB
    // cand scratch lives in the w16 region: fully consumed by select_win
    // BEFORE convert_w writes w16 (launch-ordered); no overlap with x16.
    u32* cand  = (u32*)w16;                                  // 4 MB

    hipMemsetAsync(scal, 0, 64, stream);

    front_fused_kernel<<<3072, 256, 0, stream>>>((const uint4*)w, (const f32x4*)x,
                                                 cand, x16, scal);
    select_win_kernel<<<1, 1024, 0, stream>>>(cand, (const uint4*)w, scal);
    convert_w_kernel<<<2048, 256, 0, stream>>>((const u32x4*)w, w16, scal);

    gemm8p<<<512, 512, 0, stream>>>(x16, w16, bias, out);
}

// Round 10
// 343.307 us; speedup vs baseline: 1.4984x; 1.0125x over previous
//
#include <hip/hip_runtime.h>

#define IN_F   4096
#define OUT_F  4096
#define N_TOK  8192
#define NW     (OUT_F * IN_F)          // 16777216 weight elements
#define SEL_TARGET 8388608u            // 0-based ascending index of kth (= NW - MAX_ITER)
#define CAND_CAP (1u << 20)            // 1M keys (expected ~205K)

// Magnitude window (f32 bit patterns, sign stripped): kth is the median of
// |w| ~ U[0, 2^-6)  =>  ~2^-7 = 0x3C000000 with sigma ~1.9e-6.  Window ~±50 sigma.
#define LO_BITS 0x3BFCA000u            // 0.0077133
#define HI_BITS 0x3C018000u            // 0.0079041

typedef unsigned int  u32;
typedef unsigned short u16;

typedef __bf16 bf16x8 __attribute__((ext_vector_type(8)));
typedef float  f32x4  __attribute__((ext_vector_type(4)));
typedef u32    u32x4  __attribute__((ext_vector_type(4)));   // nt-load capable

// scal layout: [2]=kth bits  [3]=win cand count  [4]=count below LO
//              [6]=overflow flag  [7]=fallback gate
// ---------- helpers ----------
__device__ inline u16 f2bf_rne(float f) {
    u32 u = __float_as_uint(f);
    u32 r = (u + 0x7fffu + ((u >> 16) & 1u)) >> 16;
    return (u16)r;
}

// ---------- fused front-end ----------
// blocks 0-1023:   scan w -> write w16 (0 below LO, bf16 otherwise), count<LO,
//                  compact (key,pos) of window entries
// blocks 1024-3071: convert x -> bf16
__global__ __launch_bounds__(256) void front_fused_kernel(
    const uint4* __restrict__ wb, const f32x4* __restrict__ xb,
    u16* __restrict__ w16, u16* __restrict__ x16,
    u32* __restrict__ cand, u32* __restrict__ cpos,
    u32* __restrict__ scal) {
    if (blockIdx.x < 1024) {
        __shared__ u32 lbuf[4096];
        __shared__ u32 lpos[4096];
        __shared__ u32 lcnt, gbase, lblw;
        if (threadIdx.x == 0) { lcnt = 0; lblw = 0; }
        __syncthreads();

        const int base = blockIdx.x * 4096;   // uint4 units; 1024 blocks * 4096 = NW/4
        u32 cntb = 0;
        #pragma unroll 4
        for (int j = 0; j < 16; j++) {
            const int vi = base + threadIdx.x + j * 256;
            uint4 v = wb[vi];
            u32 k[4] = {v.x & 0x7fffffffu, v.y & 0x7fffffffu,
                        v.z & 0x7fffffffu, v.w & 0x7fffffffu};
            u32 r[4] = {v.x, v.y, v.z, v.w};
            ushort4 o;
            u16* op = (u16*)&o;
            #pragma unroll
            for (int e = 0; e < 4; e++) {
                u32 kk = k[e];
                cntb += (kk < LO_BITS) ? 1u : 0u;
                // provisional mask at LO: exact for all entries outside the window
                op[e] = (kk >= LO_BITS) ? f2bf_rne(__uint_as_float(r[e])) : (u16)0;
                if (kk >= LO_BITS && kk < HI_BITS) {
                    u32 idx = atomicAdd(&lcnt, 1u);
                    if (idx < 4096) { lbuf[idx] = kk; lpos[idx] = (u32)vi * 4u + e; }
                    else scal[6] = 1u;                 // per-block overflow -> fallback
                }
            }
            *(ushort4*)&w16[(size_t)vi * 4] = o;
        }
        #pragma unroll
        for (int off = 32; off; off >>= 1) cntb += __shfl_down(cntb, off);
        if ((threadIdx.x & 63) == 0) atomicAdd(&lblw, cntb);
        __syncthreads();
        if (threadIdx.x == 0) {
            gbase = atomicAdd(&scal[3], min(lcnt, 4096u));
            atomicAdd(&scal[4], lblw);
        }
        __syncthreads();
        const u32 n = min(lcnt, 4096u), gb = gbase;
        for (u32 i = threadIdx.x; i < n; i += 256)
            if (gb + i < CAND_CAP) { cand[gb + i] = lbuf[i]; cpos[gb + i] = lpos[i]; }
    } else {
        const int stride = 2048 * 256;
        for (int i = (blockIdx.x - 1024) * 256 + threadIdx.x;
             i < (N_TOK * IN_F) / 4; i += stride) {
            f32x4 v = __builtin_nontemporal_load(&xb[i]);   // read-once stream
            ushort4 o;
            o.x = f2bf_rne(v.x);
            o.y = f2bf_rne(v.y);
            o.z = f2bf_rne(v.z);
            o.w = f2bf_rne(v.w);
            *(ushort4*)&x16[(size_t)i * 4] = o;
        }
    }
}

// ---------- exact kth among window candidates (1 block) ----------
#define SCAN1024(part, t)                                            \
    do { _Pragma("unroll")                                           \
        for (int off_ = 1; off_ < 1024; off_ <<= 1) {                \
            u32 v_ = ((t) >= off_) ? part[(t) - off_] : 0u;          \
            __syncthreads();                                         \
            part[t] += v_;                                           \
            __syncthreads();                                         \
        } } while (0)

__global__ __launch_bounds__(1024) void select_win_kernel(const u32* __restrict__ cand,
                                                          const uint4* __restrict__ wb,
                                                          u32* __restrict__ scal) {
    __shared__ u32 h[2048];
    __shared__ u32 part[1024];
    __shared__ u32 sh[2];
    const int t = threadIdx.x;
    const u32 n = scal[3], below = scal[4], ovf = scal[6];
    const bool valid = (n > 0) && (n <= CAND_CAP) && (ovf == 0) &&
                       (below <= SEL_TARGET) && (SEL_TARGET < below + n);

    if (valid) {
        u32 tgt = SEL_TARGET - below;
        const uint4* c4 = (const uint4*)cand;
        const u32 n4 = n >> 2;

        // L1: 624 bins over (key - LO) >> 9  (contention-free: <=512/bin)
        h[t] = 0; h[t + 1024] = 0;
        __syncthreads();
        for (u32 i = t; i < n4; i += 1024) {
            uint4 v = c4[i];
            atomicAdd(&h[(v.x - LO_BITS) >> 9], 1u);
            atomicAdd(&h[(v.y - LO_BITS) >> 9], 1u);
            atomicAdd(&h[(v.z - LO_BITS) >> 9], 1u);
            atomicAdd(&h[(v.w - LO_BITS) >> 9], 1u);
        }
        for (u32 i = (n4 << 2) + t; i < n; i += 1024)
            atomicAdd(&h[(cand[i] - LO_BITS) >> 9], 1u);
        __syncthreads();
        u32 c = h[t];
        part[t] = c;
        __syncthreads();
        SCAN1024(part, t);
        u32 cum = (t == 0) ? 0u : part[t - 1];
        if (tgt >= cum && tgt < cum + c) { sh[0] = (u32)t; sh[1] = tgt - cum; }
        __syncthreads();
        const u32 b1 = sh[0];
        tgt = sh[1];
        __syncthreads();

        // L2: exact — 512 bins over (key - LO) & 511, filtered to b1
        h[t] = 0; h[t + 1024] = 0;
        __syncthreads();
        for (u32 i = t; i < n4; i += 1024) {
            uint4 v = c4[i];
            u32 d0 = v.x - LO_BITS, d1 = v.y - LO_BITS,
                d2 = v.z - LO_BITS, d3 = v.w - LO_BITS;
            if ((d0 >> 9) == b1) atomicAdd(&h[d0 & 511u], 1u);
            if ((d1 >> 9) == b1) atomicAdd(&h[d1 & 511u], 1u);
            if ((d2 >> 9) == b1) atomicAdd(&h[d2 & 511u], 1u);
            if ((d3 >> 9) == b1) atomicAdd(&h[d3 & 511u], 1u);
        }
        for (u32 i = (n4 << 2) + t; i < n; i += 1024) {
            u32 d = cand[i] - LO_BITS;
            if ((d >> 9) == b1) atomicAdd(&h[d & 511u], 1u);
        }
        __syncthreads();
        c = (t < 512) ? h[t] : 0u;
        part[t] = c;
        __syncthreads();
        SCAN1024(part, t);
        cum = (t == 0) ? 0u : part[t - 1];
        if (tgt >= cum && tgt < cum + c)
            scal[2] = LO_BITS + (b1 << 9) + (u32)t;   // kth |w| bit pattern
        return;
    }

    // ---- embedded exact fallback (single block, 3-level radix over all keys).
    // Never taken for the expected distribution; correct (slow) otherwise.
    if (t == 0) scal[7] = 1u;    // finalize_w must do a full rewrite
    u32 tgt = SEL_TARGET;
    const int nvec = NW / 4;
    h[t] = 0; h[t + 1024] = 0;
    __syncthreads();
    for (int i = t; i < nvec; i += 1024) {
        uint4 v = wb[i];
        atomicAdd(&h[(v.x & 0x7fffffffu) >> 20], 1u);
        atomicAdd(&h[(v.y & 0x7fffffffu) >> 20], 1u);
        atomicAdd(&h[(v.z & 0x7fffffffu) >> 20], 1u);
        atomicAdd(&h[(v.w & 0x7fffffffu) >> 20], 1u);
    }
    __syncthreads();
    u32 a0 = h[2 * t], a1 = h[2 * t + 1];
    part[t] = a0 + a1;
    __syncthreads();
    SCAN1024(part, t);
    u32 cum = (t == 0) ? 0u : part[t - 1];
    if (tgt >= cum && tgt < cum + a0) { sh[0] = (u32)(2 * t);     sh[1] = tgt - cum; }
    cum += a0;
    if (tgt >= cum && tgt < cum + a1) { sh[0] = (u32)(2 * t + 1); sh[1] = tgt - cum; }
    __syncthreads();
    const u32 b1f = sh[0];
    tgt = sh[1];
    __syncthreads();

    h[t] = 0; h[t + 1024] = 0;
    __syncthreads();
    for (int i = t; i < nvec; i += 1024) {
        uint4 v = wb[i];
        u32 k[4] = {v.x & 0x7fffffffu, v.y & 0x7fffffffu,
                    v.z & 0x7fffffffu, v.w & 0x7fffffffu};
        #pragma unroll
        for (int e = 0; e < 4; e++)
            if ((k[e] >> 20) == b1f) atomicAdd(&h[(k[e] >> 9) & 2047u], 1u);
    }
    __syncthreads();
    a0 = h[2 * t]; a1 = h[2 * t + 1];
    part[t] = a0 + a1;
    __syncthreads();
    SCAN1024(part, t);
    cum = (t == 0) ? 0u : part[t - 1];
    if (tgt >= cum && tgt < cum + a0) { sh[0] = (u32)(2 * t);     sh[1] = tgt - cum; }
    cum += a0;
    if (tgt >= cum && tgt < cum + a1) { sh[0] = (u32)(2 * t + 1); sh[1] = tgt - cum; }
    __syncthreads();
    const u32 pfx22 = (b1f << 11) | sh[0];
    tgt = sh[1];
    __syncthreads();

    h[t] = 0; h[t + 1024] = 0;
    __syncthreads();
    for (int i = t; i < nvec; i += 1024) {
        uint4 v = wb[i];
        u32 k[4] = {v.x & 0x7fffffffu, v.y & 0x7fffffffu,
                    v.z & 0x7fffffffu, v.w & 0x7fffffffu};
        #pragma unroll
        for (int e = 0; e < 4; e++)
            if ((k[e] >> 9) == pfx22) atomicAdd(&h[k[e] & 511u], 1u);
    }
    __syncthreads();
    u32 c = (t < 512) ? h[t] : 0u;
    part[t] = c;
    __syncthreads();
    SCAN1024(part, t);
    cum = (t == 0) ? 0u : part[t - 1];
    if (tgt >= cum && tgt < cum + c)
        scal[2] = (pfx22 << 9) | (u32)t;
}

// ---------- finalize w16 ----------
// normal path: zero the window candidates below kth (<=1M scattered u16 writes)
// fallback path (scal[7]==1): full masked rewrite from w
__global__ __launch_bounds__(256) void finalize_w_kernel(
    const u32* __restrict__ cand, const u32* __restrict__ cpos,
    const u32x4* __restrict__ wb, u16* __restrict__ w16,
    const u32* __restrict__ scal) {
    const u32 kth = scal[2];
    const u32 stride = gridDim.x * blockDim.x;
    if (scal[7] == 1u) {
        const u32 nvec = NW / 4;
        for (u32 i = blockIdx.x * blockDim.x + threadIdx.x; i < nvec; i += stride) {
            u32x4 v = __builtin_nontemporal_load(&wb[i]);
            ushort4 o;
            o.x = ((v.x & 0x7fffffffu) >= kth) ? f2bf_rne(__uint_as_float(v.x)) : (u16)0;
            o.y = ((v.y & 0x7fffffffu) >= kth) ? f2bf_rne(__uint_as_float(v.y)) : (u16)0;
            o.z = ((v.z & 0x7fffffffu) >= kth) ? f2bf_rne(__uint_as_float(v.z)) : (u16)0;
            o.w = ((v.w & 0x7fffffffu) >= kth) ? f2bf_rne(__uint_as_float(v.w)) : (u16)0;
            *(ushort4*)&w16[(size_t)i * 4] = o;
        }
    } else {
        const u32 n = min(scal[3], CAND_CAP);
        for (u32 i = blockIdx.x * blockDim.x + threadIdx.x; i < n; i += stride)
            if (cand[i] < kth) w16[cpos[i]] = (u16)0;
    }
}

// ---------- 256x256 8-phase bf16 MFMA GEMM (m201 template) ----------
#define BK 64
#define NT (IN_F / BK)   // 64 K-tiles

#define ASLOT(buf, ks) (((buf) * 2 + (ks)) * 8192)
#define BSLOT(buf, ks) (32768 + ((buf) * 2 + (ks)) * 8192)

#define VMCNT(n) asm volatile("s_waitcnt vmcnt(" #n ")" ::: "memory")
#define LGKM0    asm volatile("s_waitcnt lgkmcnt(0)" ::: "memory")
#define BARR()   __builtin_amdgcn_s_barrier()

__global__ __launch_bounds__(512, 2) void gemm8p(
    const u16* __restrict__ A,
    const u16* __restrict__ B,
    const float* __restrict__ bias,
    float* __restrict__ C) {
    __shared__ u16 lds[65536];   // 128 KiB

    const int tid  = threadIdx.x;
    const int lane = tid & 63;
    const int ln15 = lane & 15;
    const int l16  = lane >> 4;
    const int wv   = tid >> 6;
    const int wr   = wv >> 2;
    const int wc   = wv & 3;
    const int wrow = wr * 128;
    const int wcol = wc * 64;

    const int bid = blockIdx.x;
    const int swz = (bid & 7) * 64 + (bid >> 3);
    const int by  = swz >> 4;
    const int bx  = swz & 15;
    const int arow = by * 256;
    const int brow = bx * 256;

    f32x4 acc[8][4];
    #pragma unroll
    for (int m = 0; m < 8; m++)
        #pragma unroll
        for (int n = 0; n < 4; n++)
            acc[m][n] = {0.f, 0.f, 0.f, 0.f};

    #define STAGE(G, rowbase, kt, ks, slot) do {                                        \
        _Pragma("unroll")                                                               \
        for (int i_ = 0; i_ < 2; i_++) {                                                \
            int q_  = tid + i_ * 512;                                                   \
            int r_  = q_ >> 2;                                                          \
            int cs_ = (q_ & 3) ^ ((r_ >> 1) & 3);                                       \
            const u16* src_ = (G) + (size_t)((rowbase) + r_) * IN_F                     \
                              + (kt) * BK + (ks) * 32 + cs_ * 8;                        \
            __builtin_amdgcn_global_load_lds(                                           \
                (const __attribute__((address_space(1))) unsigned int*)src_,            \
                (__attribute__((address_space(3))) unsigned int*)&lds[(slot) + q_ * 8], \
                16, 0, 0);                                                              \
        } } while (0)

    #define READ_A(mh, ks, buf) do {                                                    \
        _Pragma("unroll")                                                               \
        for (int i_ = 0; i_ < 4; i_++) {                                                \
            int row_ = wrow + ((mh) * 4 + i_) * 16 + ln15;                              \
            int cc_  = l16 ^ ((row_ >> 1) & 3);                                         \
            aF[i_] = *(const bf16x8*)&lds[ASLOT(buf, ks) + row_ * 32 + cc_ * 8];        \
        } } while (0)

    #define READ_B(ks, buf) do {                                                       \
        _Pragma("unroll")                                                               \
        for (int i_ = 0; i_ < 4; i_++) {                                                \
            int row_ = wcol + i_ * 16 + ln15;                                           \
            int cc_  = l16 ^ ((row_ >> 1) & 3);                                         \
            bF[i_] = *(const bf16x8*)&lds[BSLOT(buf, ks) + row_ * 32 + cc_ * 8];        \
        } } while (0)

    #define MFMAQ(mh) do {                                                              \
        __builtin_amdgcn_s_setprio(1);                                                  \
        _Pragma("unroll")                                                               \
        for (int i_ = 0; i_ < 4; i_++)                                                  \
            _Pragma("unroll")                                                           \
            for (int n_ = 0; n_ < 4; n_++)                                              \
                acc[(mh) * 4 + i_][n_] = __builtin_amdgcn_mfma_f32_16x16x32_bf16(       \
                    aF[i_], bF[n_], acc[(mh) * 4 + i_][n_], 0, 0, 0);                   \
        __builtin_amdgcn_s_setprio(0);                                                  \
    } while (0)

    STAGE(B, brow, 0, 0, BSLOT(0, 0));
    STAGE(A, arow, 0, 0, ASLOT(0, 0));
    STAGE(B, brow, 0, 1, BSLOT(0, 1));
    STAGE(A, arow, 0, 1, ASLOT(0, 1));
    VMCNT(4);
    STAGE(B, brow, 1, 0, BSLOT(1, 0));
    STAGE(A, arow, 1, 0, ASLOT(1, 0));
    STAGE(B, brow, 1, 1, BSLOT(1, 1));
    VMCNT(6);
    BARR();

    bf16x8 aF[4], bF[4];

    #pragma unroll 1
    for (int it = 0; it < NT / 2; it++) {
        const int t0 = 2 * it;
        const int ka = t0 + 1;
        const int kb = (t0 + 2 < NT) ? t0 + 2 : NT - 1;
        const int kc = (t0 + 3 < NT) ? t0 + 3 : NT - 1;

        READ_A(0, 0, 0); READ_B(0, 0);
        STAGE(A, arow, ka, 1, ASLOT(1, 1));
        BARR(); LGKM0; MFMAQ(0); BARR();
        READ_A(1, 0, 0);
        STAGE(B, brow, kb, 0, BSLOT(0, 0));
        BARR(); LGKM0; MFMAQ(1); BARR();
        READ_A(0, 1, 0); READ_B(1, 0);
        STAGE(A, arow, kb, 0, ASLOT(0, 0));
        BARR(); LGKM0; MFMAQ(0); BARR();
        READ_A(1, 1, 0);
        STAGE(B, brow, kb, 1, BSLOT(0, 1));
        VMCNT(6);
        BARR(); LGKM0; MFMAQ(1); BARR();

        READ_A(0, 0, 1); READ_B(0, 1);
        STAGE(A, arow, kb, 1, ASLOT(0, 1));
        BARR(); LGKM0; MFMAQ(0); BARR();
        READ_A(1, 0, 1);
        STAGE(B, brow, kc, 0, BSLOT(1, 0));
        BARR(); LGKM0; MFMAQ(1); BARR();
        READ_A(0, 1, 1); READ_B(1, 1);
        STAGE(A, arow, kc, 0, ASLOT(1, 0));
        BARR(); LGKM0; MFMAQ(0); BARR();
        READ_A(1, 1, 1);
        STAGE(B, brow, kc, 1, BSLOT(1, 1));
        VMCNT(6);
        BARR(); LGKM0; MFMAQ(1); BARR();
    }
    VMCNT(0);

    // epilogue: nt stores — C is never re-read; keep L2/L3 for A/B panels
    const int cr = l16 * 4;
    #pragma unroll
    for (int n = 0; n < 4; n++) {
        int col = brow + wcol + n * 16 + ln15;
        float bv = bias[col];
        #pragma unroll
        for (int m = 0; m < 8; m++) {
            int r0 = arow + wrow + m * 16 + cr;
            #pragma unroll
            for (int j = 0; j < 4; j++) {
                float vv = acc[m][n][j] + bv;
                __builtin_nontemporal_store(vv, &C[(size_t)(r0 + j) * OUT_F + col]);
            }
        }
    }
}

// ---------- launch ----------
extern "C" void kernel_launch(void* const* d_in, const int* in_sizes, int n_in,
                              void* d_out, int out_size, void* d_ws, size_t ws_size,
                              hipStream_t stream) {
    const float* x    = (const float*)d_in[0];
    const float* w    = (const float*)d_in[1];
    const float* bias = (const float*)d_in[2];
    float* out = (float*)d_out;

    char* ws = (char*)d_ws;
    u32* scal  = (u32*)(ws + 0);                             // 16 u32
    u16* w16   = (u16*)(ws + 65536);                         // 33.5 MB
    u16* x16   = (u16*)(ws + 65536 + (size_t)NW * 2);        // 67 MB
    // cand/cpos live in d_out (134 MB): read only by select_win/finalize_w,
    // fully overwritten by gemm8p afterwards.  8 MB total.
    u32* cand  = (u32*)out;                                  // 4 MB
    u32* cpos  = cand + CAND_CAP;                            // 4 MB

    hipMemsetAsync(scal, 0, 64, stream);

    front_fused_kernel<<<3072, 256, 0, stream>>>((const uint4*)w, (const f32x4*)x,
                                                 w16, x16, cand, cpos, scal);
    select_win_kernel<<<1, 1024, 0, stream>>>(cand, (const uint4*)w, scal);
    finalize_w_kernel<<<2048, 256, 0, stream>>>(cand, cpos, (const u32x4*)w,
                                                w16, scal);

    gemm8p<<<512, 512, 0, stream>>>(x16, w16, bias, out);
}

// Round 11
// 332.188 us; speedup vs baseline: 1.5485x; 1.0335x over previous
//
#include <hip/hip_runtime.h>

#define IN_F   4096
#define OUT_F  4096
#define N_TOK  8192
#define NW     (OUT_F * IN_F)          // 16777216 weight elements
#define SEL_TARGET 8388608u            // 0-based ascending index of kth (= NW - MAX_ITER)
#define CAND_CAP (1u << 20)            // 1M keys (expected ~205K)

// Magnitude window (f32 bit patterns, sign stripped): kth is the median of
// |w| ~ U[0, 2^-6)  =>  ~2^-7 = 0x3C000000 with sigma ~1.9e-6.  Window ~±50 sigma.
#define LO_BITS 0x3BFCA000u            // 0.0077133
#define HI_BITS 0x3C018000u            // 0.0079041

typedef unsigned int  u32;
typedef unsigned short u16;

typedef __bf16 bf16x8 __attribute__((ext_vector_type(8)));
typedef float  f32x4  __attribute__((ext_vector_type(4)));
typedef u32    u32x4  __attribute__((ext_vector_type(4)));   // nt-load capable

// scal layout: [2]=kth bits  [3]=win cand count  [4]=count below LO
//              [6]=overflow flag  [7]=fallback gate
// ---------- helpers ----------
__device__ inline u16 f2bf_rne(float f) {
    u32 u = __float_as_uint(f);
    u32 r = (u + 0x7fffu + ((u >> 16) & 1u)) >> 16;
    return (u16)r;
}

// ---------- K1: w-scan — provisional w16 write, count<LO, window compact ----------
__global__ __launch_bounds__(256) void scanw_kernel(
    const uint4* __restrict__ wb, u16* __restrict__ w16,
    u32* __restrict__ cand, u32* __restrict__ cpos,
    u32* __restrict__ scal) {
    __shared__ u32 lbuf[4096];
    __shared__ u32 lpos[4096];
    __shared__ u32 lcnt, gbase, lblw;
    if (threadIdx.x == 0) { lcnt = 0; lblw = 0; }
    __syncthreads();

    const int base = blockIdx.x * 4096;   // uint4 units; 1024 blocks * 4096 = NW/4
    u32 cntb = 0;
    #pragma unroll 4
    for (int j = 0; j < 16; j++) {
        const int vi = base + threadIdx.x + j * 256;
        uint4 v = wb[vi];
        u32 k[4] = {v.x & 0x7fffffffu, v.y & 0x7fffffffu,
                    v.z & 0x7fffffffu, v.w & 0x7fffffffu};
        u32 r[4] = {v.x, v.y, v.z, v.w};
        ushort4 o;
        u16* op = (u16*)&o;
        #pragma unroll
        for (int e = 0; e < 4; e++) {
            u32 kk = k[e];
            cntb += (kk < LO_BITS) ? 1u : 0u;
            // provisional mask at LO: exact for all entries outside the window
            op[e] = (kk >= LO_BITS) ? f2bf_rne(__uint_as_float(r[e])) : (u16)0;
            if (kk >= LO_BITS && kk < HI_BITS) {
                u32 idx = atomicAdd(&lcnt, 1u);
                if (idx < 4096) { lbuf[idx] = kk; lpos[idx] = (u32)vi * 4u + e; }
                else scal[6] = 1u;                 // per-block overflow -> fallback
            }
        }
        *(ushort4*)&w16[(size_t)vi * 4] = o;
    }
    #pragma unroll
    for (int off = 32; off; off >>= 1) cntb += __shfl_down(cntb, off);
    if ((threadIdx.x & 63) == 0) atomicAdd(&lblw, cntb);
    __syncthreads();
    if (threadIdx.x == 0) {
        gbase = atomicAdd(&scal[3], min(lcnt, 4096u));
        atomicAdd(&scal[4], lblw);
    }
    __syncthreads();
    const u32 n = min(lcnt, 4096u), gb = gbase;
    for (u32 i = threadIdx.x; i < n; i += 256)
        if (gb + i < CAND_CAP) { cand[gb + i] = lbuf[i]; cpos[gb + i] = lpos[i]; }
}

// ---------- K2: block 0 = exact kth among window candidates; blocks 1..2048 = x->bf16 ----------
#define SCAN1024(part, t)                                            \
    do { _Pragma("unroll")                                           \
        for (int off_ = 1; off_ < 1024; off_ <<= 1) {                \
            u32 v_ = ((t) >= off_) ? part[(t) - off_] : 0u;          \
            __syncthreads();                                         \
            part[t] += v_;                                           \
            __syncthreads();                                         \
        } } while (0)

__global__ __launch_bounds__(1024) void mid_kernel(const u32* __restrict__ cand,
                                                   const uint4* __restrict__ wb,
                                                   const f32x4* __restrict__ xb,
                                                   u16* __restrict__ x16,
                                                   u32* __restrict__ scal) {
    if (blockIdx.x != 0) {
        const int stride = 2048 * 1024;
        for (int i = (blockIdx.x - 1) * 1024 + threadIdx.x;
             i < (N_TOK * IN_F) / 4; i += stride) {
            f32x4 v = __builtin_nontemporal_load(&xb[i]);   // read-once stream
            ushort4 o;
            o.x = f2bf_rne(v.x);
            o.y = f2bf_rne(v.y);
            o.z = f2bf_rne(v.z);
            o.w = f2bf_rne(v.w);
            *(ushort4*)&x16[(size_t)i * 4] = o;
        }
        return;
    }

    __shared__ u32 h[2048];
    __shared__ u32 part[1024];
    __shared__ u32 sh[2];
    const int t = threadIdx.x;
    const u32 n = scal[3], below = scal[4], ovf = scal[6];
    const bool valid = (n > 0) && (n <= CAND_CAP) && (ovf == 0) &&
                       (below <= SEL_TARGET) && (SEL_TARGET < below + n);

    if (valid) {
        u32 tgt = SEL_TARGET - below;
        const uint4* c4 = (const uint4*)cand;
        const u32 n4 = n >> 2;

        // L1: 624 bins over (key - LO) >> 9  (contention-free: <=512/bin)
        h[t] = 0; h[t + 1024] = 0;
        __syncthreads();
        for (u32 i = t; i < n4; i += 1024) {
            uint4 v = c4[i];
            atomicAdd(&h[(v.x - LO_BITS) >> 9], 1u);
            atomicAdd(&h[(v.y - LO_BITS) >> 9], 1u);
            atomicAdd(&h[(v.z - LO_BITS) >> 9], 1u);
            atomicAdd(&h[(v.w - LO_BITS) >> 9], 1u);
        }
        for (u32 i = (n4 << 2) + t; i < n; i += 1024)
            atomicAdd(&h[(cand[i] - LO_BITS) >> 9], 1u);
        __syncthreads();
        u32 c = h[t];
        part[t] = c;
        __syncthreads();
        SCAN1024(part, t);
        u32 cum = (t == 0) ? 0u : part[t - 1];
        if (tgt >= cum && tgt < cum + c) { sh[0] = (u32)t; sh[1] = tgt - cum; }
        __syncthreads();
        const u32 b1 = sh[0];
        tgt = sh[1];
        __syncthreads();

        // L2: exact — 512 bins over (key - LO) & 511, filtered to b1
        h[t] = 0; h[t + 1024] = 0;
        __syncthreads();
        for (u32 i = t; i < n4; i += 1024) {
            uint4 v = c4[i];
            u32 d0 = v.x - LO_BITS, d1 = v.y - LO_BITS,
                d2 = v.z - LO_BITS, d3 = v.w - LO_BITS;
            if ((d0 >> 9) == b1) atomicAdd(&h[d0 & 511u], 1u);
            if ((d1 >> 9) == b1) atomicAdd(&h[d1 & 511u], 1u);
            if ((d2 >> 9) == b1) atomicAdd(&h[d2 & 511u], 1u);
            if ((d3 >> 9) == b1) atomicAdd(&h[d3 & 511u], 1u);
        }
        for (u32 i = (n4 << 2) + t; i < n; i += 1024) {
            u32 d = cand[i] - LO_BITS;
            if ((d >> 9) == b1) atomicAdd(&h[d & 511u], 1u);
        }
        __syncthreads();
        c = (t < 512) ? h[t] : 0u;
        part[t] = c;
        __syncthreads();
        SCAN1024(part, t);
        cum = (t == 0) ? 0u : part[t - 1];
        if (tgt >= cum && tgt < cum + c)
            scal[2] = LO_BITS + (b1 << 9) + (u32)t;   // kth |w| bit pattern
        return;
    }

    // ---- embedded exact fallback (single block, 3-level radix over all keys).
    // Never taken for the expected distribution; correct (slow) otherwise.
    if (t == 0) scal[7] = 1u;    // finalize_w must do a full rewrite
    u32 tgt = SEL_TARGET;
    const int nvec = NW / 4;
    h[t] = 0; h[t + 1024] = 0;
    __syncthreads();
    for (int i = t; i < nvec; i += 1024) {
        uint4 v = wb[i];
        atomicAdd(&h[(v.x & 0x7fffffffu) >> 20], 1u);
        atomicAdd(&h[(v.y & 0x7fffffffu) >> 20], 1u);
        atomicAdd(&h[(v.z & 0x7fffffffu) >> 20], 1u);
        atomicAdd(&h[(v.w & 0x7fffffffu) >> 20], 1u);
    }
    __syncthreads();
    u32 a0 = h[2 * t], a1 = h[2 * t + 1];
    part[t] = a0 + a1;
    __syncthreads();
    SCAN1024(part, t);
    u32 cum = (t == 0) ? 0u : part[t - 1];
    if (tgt >= cum && tgt < cum + a0) { sh[0] = (u32)(2 * t);     sh[1] = tgt - cum; }
    cum += a0;
    if (tgt >= cum && tgt < cum + a1) { sh[0] = (u32)(2 * t + 1); sh[1] = tgt - cum; }
    __syncthreads();
    const u32 b1f = sh[0];
    tgt = sh[1];
    __syncthreads();

    h[t] = 0; h[t + 1024] = 0;
    __syncthreads();
    for (int i = t; i < nvec; i += 1024) {
        uint4 v = wb[i];
        u32 k[4] = {v.x & 0x7fffffffu, v.y & 0x7fffffffu,
                    v.z & 0x7fffffffu, v.w & 0x7fffffffu};
        #pragma unroll
        for (int e = 0; e < 4; e++)
            if ((k[e] >> 20) == b1f) atomicAdd(&h[(k[e] >> 9) & 2047u], 1u);
    }
    __syncthreads();
    a0 = h[2 * t]; a1 = h[2 * t + 1];
    part[t] = a0 + a1;
    __syncthreads();
    SCAN1024(part, t);
    cum = (t == 0) ? 0u : part[t - 1];
    if (tgt >= cum && tgt < cum + a0) { sh[0] = (u32)(2 * t);     sh[1] = tgt - cum; }
    cum += a0;
    if (tgt >= cum && tgt < cum + a1) { sh[0] = (u32)(2 * t + 1); sh[1] = tgt - cum; }
    __syncthreads();
    const u32 pfx22 = (b1f << 11) | sh[0];
    tgt = sh[1];
    __syncthreads();

    h[t] = 0; h[t + 1024] = 0;
    __syncthreads();
    for (int i = t; i < nvec; i += 1024) {
        uint4 v = wb[i];
        u32 k[4] = {v.x & 0x7fffffffu, v.y & 0x7fffffffu,
                    v.z & 0x7fffffffu, v.w & 0x7fffffffu};
        #pragma unroll
        for (int e = 0; e < 4; e++)
            if ((k[e] >> 9) == pfx22) atomicAdd(&h[k[e] & 511u], 1u);
    }
    __syncthreads();
    u32 c = (t < 512) ? h[t] : 0u;
    part[t] = c;
    __syncthreads();
    SCAN1024(part, t);
    cum = (t == 0) ? 0u : part[t - 1];
    if (tgt >= cum && tgt < cum + c)
        scal[2] = (pfx22 << 9) | (u32)t;
}

// ---------- K3: finalize w16 ----------
// normal path: zero the window candidates below kth (<=1M scattered u16 writes)
// fallback path (scal[7]==1): full masked rewrite from w
__global__ __launch_bounds__(256) void finalize_w_kernel(
    const u32* __restrict__ cand, const u32* __restrict__ cpos,
    const u32x4* __restrict__ wb, u16* __restrict__ w16,
    const u32* __restrict__ scal) {
    const u32 kth = scal[2];
    const u32 stride = gridDim.x * blockDim.x;
    if (scal[7] == 1u) {
        const u32 nvec = NW / 4;
        for (u32 i = blockIdx.x * blockDim.x + threadIdx.x; i < nvec; i += stride) {
            u32x4 v = __builtin_nontemporal_load(&wb[i]);
            ushort4 o;
            o.x = ((v.x & 0x7fffffffu) >= kth) ? f2bf_rne(__uint_as_float(v.x)) : (u16)0;
            o.y = ((v.y & 0x7fffffffu) >= kth) ? f2bf_rne(__uint_as_float(v.y)) : (u16)0;
            o.z = ((v.z & 0x7fffffffu) >= kth) ? f2bf_rne(__uint_as_float(v.z)) : (u16)0;
            o.w = ((v.w & 0x7fffffffu) >= kth) ? f2bf_rne(__uint_as_float(v.w)) : (u16)0;
            *(ushort4*)&w16[(size_t)i * 4] = o;
        }
    } else {
        const u32 n = min(scal[3], CAND_CAP);
        for (u32 i = blockIdx.x * blockDim.x + threadIdx.x; i < n; i += stride)
            if (cand[i] < kth) w16[cpos[i]] = (u16)0;
    }
}

// ---------- K4: 256x256 8-phase bf16 MFMA GEMM (m201 template, frozen) ----------
#define BK 64
#define NT (IN_F / BK)   // 64 K-tiles

#define ASLOT(buf, ks) (((buf) * 2 + (ks)) * 8192)
#define BSLOT(buf, ks) (32768 + ((buf) * 2 + (ks)) * 8192)

#define VMCNT(n) asm volatile("s_waitcnt vmcnt(" #n ")" ::: "memory")
#define LGKM0    asm volatile("s_waitcnt lgkmcnt(0)" ::: "memory")
#define BARR()   __builtin_amdgcn_s_barrier()

__global__ __launch_bounds__(512, 2) void gemm8p(
    const u16* __restrict__ A,
    const u16* __restrict__ B,
    const float* __restrict__ bias,
    float* __restrict__ C) {
    __shared__ u16 lds[65536];   // 128 KiB

    const int tid  = threadIdx.x;
    const int lane = tid & 63;
    const int ln15 = lane & 15;
    const int l16  = lane >> 4;
    const int wv   = tid >> 6;
    const int wr   = wv >> 2;
    const int wc   = wv & 3;
    const int wrow = wr * 128;
    const int wcol = wc * 64;

    const int bid = blockIdx.x;
    const int swz = (bid & 7) * 64 + (bid >> 3);
    const int by  = swz >> 4;
    const int bx  = swz & 15;
    const int arow = by * 256;
    const int brow = bx * 256;

    f32x4 acc[8][4];
    #pragma unroll
    for (int m = 0; m < 8; m++)
        #pragma unroll
        for (int n = 0; n < 4; n++)
            acc[m][n] = {0.f, 0.f, 0.f, 0.f};

    #define STAGE(G, rowbase, kt, ks, slot) do {                                        \
        _Pragma("unroll")                                                               \
        for (int i_ = 0; i_ < 2; i_++) {                                                \
            int q_  = tid + i_ * 512;                                                   \
            int r_  = q_ >> 2;                                                          \
            int cs_ = (q_ & 3) ^ ((r_ >> 1) & 3);                                       \
            const u16* src_ = (G) + (size_t)((rowbase) + r_) * IN_F                     \
                              + (kt) * BK + (ks) * 32 + cs_ * 8;                        \
            __builtin_amdgcn_global_load_lds(                                           \
                (const __attribute__((address_space(1))) unsigned int*)src_,            \
                (__attribute__((address_space(3))) unsigned int*)&lds[(slot) + q_ * 8], \
                16, 0, 0);                                                              \
        } } while (0)

    #define READ_A(mh, ks, buf) do {                                                    \
        _Pragma("unroll")                                                               \
        for (int i_ = 0; i_ < 4; i_++) {                                                \
            int row_ = wrow + ((mh) * 4 + i_) * 16 + ln15;                              \
            int cc_  = l16 ^ ((row_ >> 1) & 3);                                         \
            aF[i_] = *(const bf16x8*)&lds[ASLOT(buf, ks) + row_ * 32 + cc_ * 8];        \
        } } while (0)

    #define READ_B(ks, buf) do {                                                       \
        _Pragma("unroll")                                                               \
        for (int i_ = 0; i_ < 4; i_++) {                                                \
            int row_ = wcol + i_ * 16 + ln15;                                           \
            int cc_  = l16 ^ ((row_ >> 1) & 3);                                         \
            bF[i_] = *(const bf16x8*)&lds[BSLOT(buf, ks) + row_ * 32 + cc_ * 8];        \
        } } while (0)

    #define MFMAQ(mh) do {                                                              \
        __builtin_amdgcn_s_setprio(1);                                                  \
        _Pragma("unroll")                                                               \
        for (int i_ = 0; i_ < 4; i_++)                                                  \
            _Pragma("unroll")                                                           \
            for (int n_ = 0; n_ < 4; n_++)                                              \
                acc[(mh) * 4 + i_][n_] = __builtin_amdgcn_mfma_f32_16x16x32_bf16(       \
                    aF[i_], bF[n_], acc[(mh) * 4 + i_][n_], 0, 0, 0);                   \
        __builtin_amdgcn_s_setprio(0);                                                  \
    } while (0)

    STAGE(B, brow, 0, 0, BSLOT(0, 0));
    STAGE(A, arow, 0, 0, ASLOT(0, 0));
    STAGE(B, brow, 0, 1, BSLOT(0, 1));
    STAGE(A, arow, 0, 1, ASLOT(0, 1));
    VMCNT(4);
    STAGE(B, brow, 1, 0, BSLOT(1, 0));
    STAGE(A, arow, 1, 0, ASLOT(1, 0));
    STAGE(B, brow, 1, 1, BSLOT(1, 1));
    VMCNT(6);
    BARR();

    bf16x8 aF[4], bF[4];

    #pragma unroll 1
    for (int it = 0; it < NT / 2; it++) {
        const int t0 = 2 * it;
        const int ka = t0 + 1;
        const int kb = (t0 + 2 < NT) ? t0 + 2 : NT - 1;
        const int kc = (t0 + 3 < NT) ? t0 + 3 : NT - 1;

        READ_A(0, 0, 0); READ_B(0, 0);
        STAGE(A, arow, ka, 1, ASLOT(1, 1));
        BARR(); LGKM0; MFMAQ(0); BARR();
        READ_A(1, 0, 0);
        STAGE(B, brow, kb, 0, BSLOT(0, 0));
        BARR(); LGKM0; MFMAQ(1); BARR();
        READ_A(0, 1, 0); READ_B(1, 0);
        STAGE(A, arow, kb, 0, ASLOT(0, 0));
        BARR(); LGKM0; MFMAQ(0); BARR();
        READ_A(1, 1, 0);
        STAGE(B, brow, kb, 1, BSLOT(0, 1));
        VMCNT(6);
        BARR(); LGKM0; MFMAQ(1); BARR();

        READ_A(0, 0, 1); READ_B(0, 1);
        STAGE(A, arow, kb, 1, ASLOT(0, 1));
        BARR(); LGKM0; MFMAQ(0); BARR();
        READ_A(1, 0, 1);
        STAGE(B, brow, kc, 0, BSLOT(1, 0));
        BARR(); LGKM0; MFMAQ(1); BARR();
        READ_A(0, 1, 1); READ_B(1, 1);
        STAGE(A, arow, kc, 0, ASLOT(1, 0));
        BARR(); LGKM0; MFMAQ(0); BARR();
        READ_A(1, 1, 1);
        STAGE(B, brow, kc, 1, BSLOT(1, 1));
        VMCNT(6);
        BARR(); LGKM0; MFMAQ(1); BARR();
    }
    VMCNT(0);

    // epilogue: nt stores — C is never re-read; keep L2/L3 for A/B panels
    const int cr = l16 * 4;
    #pragma unroll
    for (int n = 0; n < 4; n++) {
        int col = brow + wcol + n * 16 + ln15;
        float bv = bias[col];
        #pragma unroll
        for (int m = 0; m < 8; m++) {
            int r0 = arow + wrow + m * 16 + cr;
            #pragma unroll
            for (int j = 0; j < 4; j++) {
                float vv = acc[m][n][j] + bv;
                __builtin_nontemporal_store(vv, &C[(size_t)(r0 + j) * OUT_F + col]);
            }
        }
    }
}

// ---------- launch ----------
extern "C" void kernel_launch(void* const* d_in, const int* in_sizes, int n_in,
                              void* d_out, int out_size, void* d_ws, size_t ws_size,
                              hipStream_t stream) {
    const float* x    = (const float*)d_in[0];
    const float* w    = (const float*)d_in[1];
    const float* bias = (const float*)d_in[2];
    float* out = (float*)d_out;

    char* ws = (char*)d_ws;
    u32* scal  = (u32*)(ws + 0);                             // 16 u32
    u16* w16   = (u16*)(ws + 65536);                         // 33.5 MB
    u16* x16   = (u16*)(ws + 65536 + (size_t)NW * 2);        // 67 MB
    // cand/cpos live in d_out (134 MB): read only by mid/finalize,
    // fully overwritten by gemm8p afterwards.  8 MB total.
    u32* cand  = (u32*)out;                                  // 4 MB
    u32* cpos  = cand + CAND_CAP;                            // 4 MB

    hipMemsetAsync(scal, 0, 64, stream);

    scanw_kernel<<<1024, 256, 0, stream>>>((const uint4*)w, w16, cand, cpos, scal);
    mid_kernel<<<2049, 1024, 0, stream>>>(cand, (const uint4*)w, (const f32x4*)x,
                                          x16, scal);
    finalize_w_kernel<<<2048, 256, 0, stream>>>(cand, cpos, (const u32x4*)w,
                                                w16, scal);

    gemm8p<<<512, 512, 0, stream>>>(x16, w16, bias, out);
}